// Round 1
// baseline (931.748 us; speedup 1.0000x reference)
//
#include <hip/hip_runtime.h>
#include <hip/hip_bf16.h>

// ---------------------------------------------------------------------------
// DeformableTransformerDecoderLayer on MI355X — round 0: correctness baseline
// fp32 SIMT GEMMs + flash attention + fused msdeform sampling + LN kernels.
// Workspace map (floats), T = 7200*256 = 1843200:
//   [0..T)    qplus (tgt+pos)        — later aliased by ffn_h (needs 4T exactly)
//   [T..2T)   Qb   [2T..3T) Kb   [3T..4T) Vb
//   [4T..5T)  sa   [5T..6T) saproj
//   [6T..7T)  t1   [7T..8T) qplus2 (b,q layout)
//   [8T..9T)  offbuf  [9T..10T) sampout
//   [10T..11T) ca  [11T..12T) t2  [12T..13T) ffnout
//   [13T..13T+0.92M) awlog
//   [14T..14T+13.61M) value as bf16 (BS*LMEM*256 ushorts)
// Total ≈ 158 MB.
// ---------------------------------------------------------------------------

namespace {
constexpr int D_ = 256;
constexpr int NQ_ = 900;
constexpr int BS_ = 8;
constexpr int NL_ = 4;
constexpr int NH_ = 8;
constexpr int HD_ = 32;
constexpr int DFF_ = 1024;
constexpr int MTOK = NQ_ * BS_;       // 7200
constexpr int LMEM_ = 13294;
constexpr long T = (long)MTOK * D_;   // 1843200
}

// ---------------- elementwise add (float4) ----------------
__global__ void add_vec4(const float* __restrict__ a, const float* __restrict__ b,
                         float* __restrict__ o, int n4) {
    int i = blockIdx.x * blockDim.x + threadIdx.x;
    if (i < n4) {
        float4 av = ((const float4*)a)[i];
        float4 bv = ((const float4*)b)[i];
        float4 ov;
        ov.x = av.x + bv.x; ov.y = av.y + bv.y; ov.z = av.z + bv.z; ov.w = av.w + bv.w;
        ((float4*)o)[i] = ov;
    }
}

// ---------------- generic GEMM: C[r,n] = sum_k A[arow(r),k]*W[n,k] + bias[n] ----
// arow(r) = (r/R1)*S1 + (r%R1)*S2.  W row-major (N,K).  N%64==0, K%16==0.
template<bool RELU, bool OUTBF16>
__global__ __launch_bounds__(256) void gemm_atb(
    const float* __restrict__ A, const float* __restrict__ W,
    const float* __restrict__ bias, void* __restrict__ C,
    int M, int N, int K, int R1, int S1, int S2)
{
    __shared__ float As[16][68];
    __shared__ float Ws[16][68];
    const int t = threadIdx.x;
    const int tx = t & 15, ty = t >> 4;
    const int bm = blockIdx.x, bn = blockIdx.y;
    const int lr = t >> 2;             // 0..63
    const int lk = (t & 3) * 4;        // 0,4,8,12
    const int gr = bm * 64 + lr;
    const bool rvalid = gr < M;
    const int grc = rvalid ? gr : 0;
    const long arow = (long)(grc / R1) * S1 + (long)(grc % R1) * S2;
    const float* Ap = A + arow * K + lk;
    const float* Wp = W + (long)(bn * 64 + lr) * K + lk;
    float c[4][4] = {};
    for (int kb = 0; kb < K; kb += 16) {
        float4 av = make_float4(0.f, 0.f, 0.f, 0.f);
        if (rvalid) av = *(const float4*)(Ap + kb);
        float4 wv = *(const float4*)(Wp + kb);
        __syncthreads();
        As[lk + 0][lr] = av.x; As[lk + 1][lr] = av.y; As[lk + 2][lr] = av.z; As[lk + 3][lr] = av.w;
        Ws[lk + 0][lr] = wv.x; Ws[lk + 1][lr] = wv.y; Ws[lk + 2][lr] = wv.z; Ws[lk + 3][lr] = wv.w;
        __syncthreads();
#pragma unroll
        for (int k = 0; k < 16; ++k) {
            const float4 a4 = *(const float4*)&As[k][ty * 4];
            const float4 b4 = *(const float4*)&Ws[k][tx * 4];
            const float aa[4] = {a4.x, a4.y, a4.z, a4.w};
            const float bb[4] = {b4.x, b4.y, b4.z, b4.w};
#pragma unroll
            for (int i = 0; i < 4; ++i)
#pragma unroll
                for (int j = 0; j < 4; ++j)
                    c[i][j] += aa[i] * bb[j];
        }
    }
    const int r0 = bm * 64 + ty * 4;
    const int n0 = bn * 64 + tx * 4;
#pragma unroll
    for (int i = 0; i < 4; ++i) {
        const int r = r0 + i;
        if (r < M) {
#pragma unroll
            for (int j = 0; j < 4; ++j) {
                float v = c[i][j] + bias[n0 + j];
                if (RELU) v = fmaxf(v, 0.f);
                if (OUTBF16)
                    ((__hip_bfloat16*)C)[(long)r * N + n0 + j] = __float2bfloat16(v);
                else
                    ((float*)C)[(long)r * N + n0 + j] = v;
            }
        }
    }
}

// ---------------- self-attention (flash-style, 8 queries/block) ----------------
// Qb/Kb/Vb rows are (q*BS+b), cols h*32+d.  Output sa same layout.
__global__ __launch_bounds__(256) void attn_kernel(
    const float* __restrict__ Qb, const float* __restrict__ Kb,
    const float* __restrict__ Vb, float* __restrict__ sa)
{
    __shared__ float Ks[64][33];
    __shared__ float Vs[64][33];
    __shared__ float Ss[8][64];
    const int bh = blockIdx.x;
    const int b = bh >> 3, h = bh & 7;
    const int q0 = blockIdx.y * 8;
    const int t = threadIdx.x;
    const int qi = t >> 5;      // query slot 0..7 (half-wave groups)
    const int d = t & 31;       // head dim
    const int q = q0 + qi;
    const bool active = q < NQ_;
    float qreg[32];
    {
        const float* qp = Qb + ((long)(active ? q : 0) * BS_ + b) * D_ + h * HD_;
#pragma unroll
        for (int dd = 0; dd < 32; ++dd) qreg[dd] = active ? qp[dd] : 0.f;
    }
    float m_run = -1e30f, l_run = 0.f, acc = 0.f;
    const int jld = t >> 2;           // key row this thread stages
    const int d0 = (t & 3) * 8;       // 8 dims per thread
    for (int kc = 0; kc < NQ_; kc += 64) {
        __syncthreads();
        {
            const int kk = kc + jld;
            if (kk < NQ_) {
                const float* kp = Kb + ((long)kk * BS_ + b) * D_ + h * HD_ + d0;
                const float* vp = Vb + ((long)kk * BS_ + b) * D_ + h * HD_ + d0;
                const float4 k0 = *(const float4*)kp;
                const float4 k1 = *(const float4*)(kp + 4);
                const float4 v0 = *(const float4*)vp;
                const float4 v1 = *(const float4*)(vp + 4);
                Ks[jld][d0 + 0] = k0.x; Ks[jld][d0 + 1] = k0.y; Ks[jld][d0 + 2] = k0.z; Ks[jld][d0 + 3] = k0.w;
                Ks[jld][d0 + 4] = k1.x; Ks[jld][d0 + 5] = k1.y; Ks[jld][d0 + 6] = k1.z; Ks[jld][d0 + 7] = k1.w;
                Vs[jld][d0 + 0] = v0.x; Vs[jld][d0 + 1] = v0.y; Vs[jld][d0 + 2] = v0.z; Vs[jld][d0 + 3] = v0.w;
                Vs[jld][d0 + 4] = v1.x; Vs[jld][d0 + 5] = v1.y; Vs[jld][d0 + 6] = v1.z; Vs[jld][d0 + 7] = v1.w;
            } else {
#pragma unroll
                for (int u = 0; u < 8; ++u) { Ks[jld][d0 + u] = 0.f; Vs[jld][d0 + u] = 0.f; }
            }
        }
        __syncthreads();
        float s1 = 0.f, s2 = 0.f;
#pragma unroll
        for (int dd = 0; dd < 32; ++dd) {
            s1 += qreg[dd] * Ks[d][dd];
            s2 += qreg[dd] * Ks[d + 32][dd];
        }
        const float scale = 0.17677669529663687f;  // 1/sqrt(32)
        s1 *= scale; s2 *= scale;
        if (kc + d >= NQ_) s1 = -1e30f;
        if (kc + d + 32 >= NQ_) s2 = -1e30f;
        float mloc = fmaxf(s1, s2);
#pragma unroll
        for (int off = 16; off > 0; off >>= 1) mloc = fmaxf(mloc, __shfl_xor(mloc, off));
        const float mnew = fmaxf(m_run, mloc);
        const float resc = __expf(m_run - mnew);
        const float p1 = __expf(s1 - mnew);
        const float p2 = __expf(s2 - mnew);
        float ls = p1 + p2;
#pragma unroll
        for (int off = 16; off > 0; off >>= 1) ls += __shfl_xor(ls, off);
        l_run = l_run * resc + ls;
        m_run = mnew;
        Ss[qi][d] = p1;
        Ss[qi][d + 32] = p2;        // same-wave LDS: ordered, no barrier needed
        float a = acc * resc;
#pragma unroll 8
        for (int j = 0; j < 64; ++j) a += Ss[qi][j] * Vs[j][d];
        acc = a;
    }
    if (active) sa[((long)q * BS_ + b) * D_ + h * HD_ + d] = acc / l_run;
}

// ---------------- msdeform: aw softmax + bilinear gather + weighted sum --------
__global__ __launch_bounds__(256) void msdeform_kernel(
    const float* __restrict__ awlog, const float* __restrict__ offb,
    const float* __restrict__ refp, const __hip_bfloat16* __restrict__ val,
    float* __restrict__ out)
{
    __shared__ float saw[128];
    __shared__ float redm[8], redi[8];
    __shared__ float swt[128][4];
    __shared__ int sidx[128][4];
    const int bq = blockIdx.x;        // b*NQ + q
    const int b = bq / NQ_, q = bq % NQ_;
    const int t = threadIdx.x;
    if (t < 128) saw[t] = awlog[(long)bq * 128 + t];
    __syncthreads();
    if (t < 8) {
        float mx = -1e30f;
        for (int i = 0; i < 16; ++i) mx = fmaxf(mx, saw[t * 16 + i]);
        float s = 0.f;
        for (int i = 0; i < 16; ++i) s += __expf(saw[t * 16 + i] - mx);
        redm[t] = mx; redi[t] = 1.f / s;
    }
    __syncthreads();
    if (t < 128) {
        const int h = t >> 4, lp = t & 15, l = lp >> 2, p = lp & 3;
        const float aw = __expf(saw[t] - redm[h]) * redi[h];
        const int Wi = (l == 0) ? 100 : (l == 1) ? 50 : (l == 2) ? 25 : 13;
        const int Hi = Wi;
        const int sl = (l == 0) ? 0 : (l == 1) ? 10000 : (l == 2) ? 12500 : 13125;
        const float offx = offb[(long)bq * 256 + h * 32 + l * 8 + p * 2 + 0];
        const float offy = offb[(long)bq * 256 + h * 32 + l * 8 + p * 2 + 1];
        const float refx = refp[(((long)q * BS_ + b) * NL_ + l) * 2 + 0];
        const float refy = refp[(((long)q * BS_ + b) * NL_ + l) * 2 + 1];
        const float fW = (float)Wi, fH = (float)Hi;
        const float x = (refx + offx / fW) * fW - 0.5f;
        const float y = (refy + offy / fH) * fH - 0.5f;
        const float x0f = floorf(x), y0f = floorf(y);
        const float fx = x - x0f, fy = y - y0f;
        const int ix = (int)x0f, iy = (int)y0f;
        const float wts[4] = {(1.f - fx) * (1.f - fy), fx * (1.f - fy),
                              (1.f - fx) * fy,          fx * fy};
        const int xs[4] = {ix, ix + 1, ix, ix + 1};
        const int ys[4] = {iy, iy, iy + 1, iy + 1};
#pragma unroll
        for (int tap = 0; tap < 4; ++tap) {
            const bool valid = (xs[tap] >= 0) & (xs[tap] < Wi) & (ys[tap] >= 0) & (ys[tap] < Hi);
            const int xc = min(max(xs[tap], 0), Wi - 1);
            const int yc = min(max(ys[tap], 0), Hi - 1);
            swt[t][tap] = valid ? aw * wts[tap] : 0.f;
            sidx[t][tap] = b * LMEM_ + sl + yc * Wi + xc;
        }
    }
    __syncthreads();
    const int h = t >> 5, d = t & 31;
    float acc = 0.f;
    for (int i = 0; i < 16; ++i) {
        const int j = h * 16 + i;
#pragma unroll
        for (int tap = 0; tap < 4; ++tap) {
            const float wv = swt[j][tap];
            if (wv != 0.f)
                acc += wv * __bfloat162float(val[(long)sidx[j][tap] * D_ + h * HD_ + d]);
        }
    }
    out[(long)bq * D_ + h * HD_ + d] = acc;
}

// ---------------- LayerNorm: out[r] = LN(inA[r] + inB[rb]) ; optional extra ----
// swapB: rb = (r&7)*NQ + (r>>3)  (maps (q,b)-row to (b,q)-row source)
// extraOut (if non-null): extraOut[(r&7)*NQ + r>>3] = y + pos[r]
__global__ __launch_bounds__(256) void ln_kernel(
    const float* __restrict__ inA, const float* __restrict__ inB,
    const float* __restrict__ g, const float* __restrict__ be,
    float* __restrict__ out, const float* __restrict__ pos,
    float* __restrict__ extraOut, int swapB)
{
    const int r = blockIdx.x * 4 + (threadIdx.x >> 6);
    const int lane = threadIdx.x & 63;
    long rb = r;
    if (swapB) rb = (long)(r & 7) * NQ_ + (r >> 3);
    const float4 a4 = *(const float4*)(inA + (long)r * D_ + lane * 4);
    const float4 b4 = *(const float4*)(inB + rb * D_ + lane * 4);
    float x[4] = {a4.x + b4.x, a4.y + b4.y, a4.z + b4.z, a4.w + b4.w};
    float s = x[0] + x[1] + x[2] + x[3];
#pragma unroll
    for (int off = 32; off > 0; off >>= 1) s += __shfl_xor(s, off);
    const float mu = s * (1.f / D_);
    float v = 0.f;
#pragma unroll
    for (int c = 0; c < 4; ++c) { const float dd = x[c] - mu; v += dd * dd; }
#pragma unroll
    for (int off = 32; off > 0; off >>= 1) v += __shfl_xor(v, off);
    const float rs = rsqrtf(v * (1.f / D_) + 1e-5f);
    const float4 g4 = *(const float4*)(g + lane * 4);
    const float4 e4 = *(const float4*)(be + lane * 4);
    const float gg[4] = {g4.x, g4.y, g4.z, g4.w};
    const float ee[4] = {e4.x, e4.y, e4.z, e4.w};
    float y[4];
#pragma unroll
    for (int c = 0; c < 4; ++c) y[c] = (x[c] - mu) * rs * gg[c] + ee[c];
    *(float4*)(out + (long)r * D_ + lane * 4) = make_float4(y[0], y[1], y[2], y[3]);
    if (extraOut) {
        const float4 p4 = *(const float4*)(pos + (long)r * D_ + lane * 4);
        const long er = (long)(r & 7) * NQ_ + (r >> 3);
        *(float4*)(extraOut + er * D_ + lane * 4) =
            make_float4(y[0] + p4.x, y[1] + p4.y, y[2] + p4.z, y[3] + p4.w);
    }
}

// ---------------------------------------------------------------------------
extern "C" void kernel_launch(void* const* d_in, const int* in_sizes, int n_in,
                              void* d_out, int out_size, void* d_ws, size_t ws_size,
                              hipStream_t stream) {
    const float* tgt   = (const float*)d_in[0];
    const float* pos   = (const float*)d_in[1];
    const float* refp  = (const float*)d_in[2];
    const float* mem   = (const float*)d_in[3];
    // d_in[4] spatial_shapes, d_in[5] level_start_index: compile-time constants
    const float* ipw   = (const float*)d_in[6];
    const float* ipb   = (const float*)d_in[7];
    const float* opw   = (const float*)d_in[8];
    const float* opb   = (const float*)d_in[9];
    const float* sow   = (const float*)d_in[10];
    const float* sob   = (const float*)d_in[11];
    const float* aww   = (const float*)d_in[12];
    const float* awb   = (const float*)d_in[13];
    const float* vpw   = (const float*)d_in[14];
    const float* vpb   = (const float*)d_in[15];
    const float* outpw = (const float*)d_in[16];
    const float* outpb = (const float*)d_in[17];
    const float* l1w   = (const float*)d_in[18];
    const float* l1b   = (const float*)d_in[19];
    const float* l2w   = (const float*)d_in[20];
    const float* l2b   = (const float*)d_in[21];
    const float* n1g = (const float*)d_in[22]; const float* n1be = (const float*)d_in[23];
    const float* n2g = (const float*)d_in[24]; const float* n2be = (const float*)d_in[25];
    const float* n3g = (const float*)d_in[26]; const float* n3be = (const float*)d_in[27];

    float* w = (float*)d_ws;
    float* qplus  = w;
    float* Qb     = w + T;
    float* Kb     = w + 2 * T;
    float* Vb     = w + 3 * T;
    float* sa     = w + 4 * T;
    float* saproj = w + 5 * T;
    float* t1     = w + 6 * T;
    float* qplus2 = w + 7 * T;
    float* offb   = w + 8 * T;
    float* sampo  = w + 9 * T;
    float* ca     = w + 10 * T;
    float* t2     = w + 11 * T;
    float* ffno   = w + 12 * T;
    float* awlog  = w + 13 * T;
    __hip_bfloat16* val = (__hip_bfloat16*)(w + 14 * T);
    float* ffnh   = w;  // aliases qplus/Qb/Kb/Vb (4T floats) — dead by FFN time

    const dim3 blk(256);
    const dim3 g_m(113, 4);  // 7200 rows, 256 cols

    // 1. q = tgt + pos
    add_vec4<<<1800, blk, 0, stream>>>(tgt, pos, qplus, (int)(T / 4));
    // 2-4. QKV projections
    gemm_atb<false, false><<<g_m, blk, 0, stream>>>(qplus, ipw,             ipb,           Qb, MTOK, D_, D_, MTOK, 0, 1);
    gemm_atb<false, false><<<g_m, blk, 0, stream>>>(qplus, ipw + D_ * D_,   ipb + D_,      Kb, MTOK, D_, D_, MTOK, 0, 1);
    gemm_atb<false, false><<<g_m, blk, 0, stream>>>(tgt,   ipw + 2 * D_ * D_, ipb + 2 * D_, Vb, MTOK, D_, D_, MTOK, 0, 1);
    // 5. self-attention
    attn_kernel<<<dim3(64, 113), blk, 0, stream>>>(Qb, Kb, Vb, sa);
    // 6. out_proj
    gemm_atb<false, false><<<g_m, blk, 0, stream>>>(sa, opw, opb, saproj, MTOK, D_, D_, MTOK, 0, 1);
    // 7. t1 = LN2(tgt + saproj); qplus2 = transpose(t1 + pos)
    ln_kernel<<<1800, blk, 0, stream>>>(tgt, saproj, n2g, n2be, t1, pos, qplus2, 0);
    // 8. value projection (bf16 out), rows (b, i) from memory rows (i, b)
    gemm_atb<false, true><<<dim3((BS_ * LMEM_ + 63) / 64, 4), blk, 0, stream>>>(
        mem, vpw, vpb, val, BS_ * LMEM_, D_, D_, LMEM_, 1, BS_);
    // 9-10. sampling offsets + attention-weight logits
    gemm_atb<false, false><<<g_m, blk, 0, stream>>>(qplus2, sow, sob, offb, MTOK, D_, D_, MTOK, 0, 1);
    gemm_atb<false, false><<<dim3(113, 2), blk, 0, stream>>>(qplus2, aww, awb, awlog, MTOK, 128, D_, MTOK, 0, 1);
    // 11. deformable sampling
    msdeform_kernel<<<7200, blk, 0, stream>>>(awlog, offb, refp, val, sampo);
    // 12. output projection
    gemm_atb<false, false><<<g_m, blk, 0, stream>>>(sampo, outpw, outpb, ca, MTOK, D_, D_, MTOK, 0, 1);
    // 13. t2 = LN1(t1 + ca^T)
    ln_kernel<<<1800, blk, 0, stream>>>(t1, ca, n1g, n1be, t2, nullptr, nullptr, 1);
    // 14-15. FFN
    gemm_atb<true, false><<<dim3(113, 16), blk, 0, stream>>>(t2, l1w, l1b, ffnh, MTOK, DFF_, D_, MTOK, 0, 1);
    gemm_atb<false, false><<<g_m, blk, 0, stream>>>(ffnh, l2w, l2b, ffno, MTOK, D_, DFF_, MTOK, 0, 1);
    // 16. out = LN3(t2 + ffn)
    ln_kernel<<<1800, blk, 0, stream>>>(t2, ffno, n3g, n3be, (float*)d_out, nullptr, nullptr, 0);
}

// Round 2
// 625.142 us; speedup vs baseline: 1.4905x; 1.4905x over previous
//
#include <hip/hip_runtime.h>
#include <hip/hip_bf16.h>

// ---------------------------------------------------------------------------
// DeformableTransformerDecoderLayer on MI355X — round 1: MFMA flash attention.
// Workspace map (floats), T = 7200*256 = 1843200:
//   [0..T)    qplus (tgt+pos)        — later aliased by ffn_h (needs 4T exactly)
//   [T..2T)   Qb   [2T..3T) Kb   [3T..4T) Vb
//   [4T..5T)  sa   [5T..6T) saproj
//   [6T..7T)  t1   [7T..8T) qplus2 (b,q layout)
//   [8T..9T)  offbuf  [9T..10T) sampout
//   [10T..11T) ca  [11T..12T) t2  [12T..13T) ffnout
//   [13T..13T+0.92M) awlog
//   [14T..14T+13.61M) value as bf16 (BS*LMEM*256 ushorts)
// ---------------------------------------------------------------------------

namespace {
constexpr int D_ = 256;
constexpr int NQ_ = 900;
constexpr int BS_ = 8;
constexpr int NL_ = 4;
constexpr int NH_ = 8;
constexpr int HD_ = 32;
constexpr int DFF_ = 1024;
constexpr int MTOK = NQ_ * BS_;       // 7200
constexpr int LMEM_ = 13294;
constexpr long T = (long)MTOK * D_;   // 1843200
}

typedef __attribute__((ext_vector_type(8))) short bf8_t;
typedef __attribute__((ext_vector_type(4))) float f4_t;

#define MFMA16(a, b, c) __builtin_amdgcn_mfma_f32_16x16x32_bf16((a), (b), (c), 0, 0, 0)

__device__ inline unsigned short bfbits(float x) {
    union { __hip_bfloat16 h; unsigned short u; } cv;
    cv.h = __float2bfloat16(x);
    return cv.u;
}

// ---------------- elementwise add (float4) ----------------
__global__ void add_vec4(const float* __restrict__ a, const float* __restrict__ b,
                         float* __restrict__ o, int n4) {
    int i = blockIdx.x * blockDim.x + threadIdx.x;
    if (i < n4) {
        float4 av = ((const float4*)a)[i];
        float4 bv = ((const float4*)b)[i];
        float4 ov;
        ov.x = av.x + bv.x; ov.y = av.y + bv.y; ov.z = av.z + bv.z; ov.w = av.w + bv.w;
        ((float4*)o)[i] = ov;
    }
}

// ---------------- generic GEMM: C[r,n] = sum_k A[arow(r),k]*W[n,k] + bias[n] ----
template<bool RELU, bool OUTBF16>
__global__ __launch_bounds__(256) void gemm_atb(
    const float* __restrict__ A, const float* __restrict__ W,
    const float* __restrict__ bias, void* __restrict__ C,
    int M, int N, int K, int R1, int S1, int S2)
{
    __shared__ float As[16][68];
    __shared__ float Ws[16][68];
    const int t = threadIdx.x;
    const int tx = t & 15, ty = t >> 4;
    const int bm = blockIdx.x, bn = blockIdx.y;
    const int lr = t >> 2;
    const int lk = (t & 3) * 4;
    const int gr = bm * 64 + lr;
    const bool rvalid = gr < M;
    const int grc = rvalid ? gr : 0;
    const long arow = (long)(grc / R1) * S1 + (long)(grc % R1) * S2;
    const float* Ap = A + arow * K + lk;
    const float* Wp = W + (long)(bn * 64 + lr) * K + lk;
    float c[4][4] = {};
    for (int kb = 0; kb < K; kb += 16) {
        float4 av = make_float4(0.f, 0.f, 0.f, 0.f);
        if (rvalid) av = *(const float4*)(Ap + kb);
        float4 wv = *(const float4*)(Wp + kb);
        __syncthreads();
        As[lk + 0][lr] = av.x; As[lk + 1][lr] = av.y; As[lk + 2][lr] = av.z; As[lk + 3][lr] = av.w;
        Ws[lk + 0][lr] = wv.x; Ws[lk + 1][lr] = wv.y; Ws[lk + 2][lr] = wv.z; Ws[lk + 3][lr] = wv.w;
        __syncthreads();
#pragma unroll
        for (int k = 0; k < 16; ++k) {
            const float4 a4 = *(const float4*)&As[k][ty * 4];
            const float4 b4 = *(const float4*)&Ws[k][tx * 4];
            const float aa[4] = {a4.x, a4.y, a4.z, a4.w};
            const float bb[4] = {b4.x, b4.y, b4.z, b4.w};
#pragma unroll
            for (int i = 0; i < 4; ++i)
#pragma unroll
                for (int j = 0; j < 4; ++j)
                    c[i][j] += aa[i] * bb[j];
        }
    }
    const int r0 = bm * 64 + ty * 4;
    const int n0 = bn * 64 + tx * 4;
#pragma unroll
    for (int i = 0; i < 4; ++i) {
        const int r = r0 + i;
        if (r < M) {
#pragma unroll
            for (int j = 0; j < 4; ++j) {
                float v = c[i][j] + bias[n0 + j];
                if (RELU) v = fmaxf(v, 0.f);
                if (OUTBF16)
                    ((__hip_bfloat16*)C)[(long)r * N + n0 + j] = __float2bfloat16(v);
                else
                    ((float*)C)[(long)r * N + n0 + j] = v;
            }
        }
    }
}

// ---------------- MFMA flash attention ----------------
// Grid: (64 bh, 15 q-blocks), 256 threads (4 waves × 16 q-rows each).
// Per 64-key chunk: K staged [64][32] bf16 linear; V staged transposed
// [32][64] bf16 with XOR swizzle (shortidx = r*64 + (k ^ ((r&7)<<3))).
// QK^T swapped: S^T = mfma(A=K, B=Q) -> lane holds col q=lane&15,
// rows key=(lane>>4)*4+reg. PV: O^T = mfma(A=V^T, B=P^T).
__global__ __launch_bounds__(256) void attn_mfma(
    const float* __restrict__ Qb, const float* __restrict__ Kb,
    const float* __restrict__ Vb, float* __restrict__ sa)
{
    __shared__ float smemf[2112];   // 4KB Ks + 4KB Vt; reused as 4×528f O-stage
    unsigned short* Ks = (unsigned short*)smemf;            // [64][32]
    unsigned short* Vt = (unsigned short*)(smemf + 1024);   // [32][64] swizzled
    const int t = threadIdx.x;
    const int wave = t >> 6, lane = t & 63;
    const int g = lane >> 4, c = lane & 15;
    const int b = blockIdx.x >> 3, h = blockIdx.x & 7;
    const int q0 = blockIdx.y * 64 + wave * 16;
    const int q = q0 + c;
    const bool qv = q < NQ_;

    bf8_t qf;
    {
        const float* qp = Qb + ((long)(qv ? q : 0) * BS_ + b) * D_ + h * HD_ + 8 * g;
        const float sc = 0.17677669529663687f;   // 1/sqrt(32)
        union { bf8_t v; unsigned short u[8]; } uq;
#pragma unroll
        for (int j = 0; j < 8; ++j)
            uq.u[j] = bfbits(qv ? qp[j] * sc : 0.f);
        qf = uq.v;
    }

    f4_t acc0 = {0.f, 0.f, 0.f, 0.f}, acc1 = {0.f, 0.f, 0.f, 0.f};
    float m_run = -1e30f, l_run = 0.f;
    const int sk = t >> 2, sd = (t & 3) * 8;

    for (int kc = 0; kc < NQ_; kc += 64) {
        __syncthreads();
        {   // stage K (linear) + V (transposed, swizzled)
            const int key = kc + sk;
            float kvv[8], vvv[8];
            if (key < NQ_) {
                const float* kp = Kb + ((long)key * BS_ + b) * D_ + h * HD_ + sd;
                const float* vp = Vb + ((long)key * BS_ + b) * D_ + h * HD_ + sd;
                const float4 a0 = *(const float4*)kp, a1 = *(const float4*)(kp + 4);
                const float4 b0 = *(const float4*)vp, b1 = *(const float4*)(vp + 4);
                kvv[0] = a0.x; kvv[1] = a0.y; kvv[2] = a0.z; kvv[3] = a0.w;
                kvv[4] = a1.x; kvv[5] = a1.y; kvv[6] = a1.z; kvv[7] = a1.w;
                vvv[0] = b0.x; vvv[1] = b0.y; vvv[2] = b0.z; vvv[3] = b0.w;
                vvv[4] = b1.x; vvv[5] = b1.y; vvv[6] = b1.z; vvv[7] = b1.w;
            } else {
#pragma unroll
                for (int u = 0; u < 8; ++u) { kvv[u] = 0.f; vvv[u] = 0.f; }
            }
            union { bf8_t v; unsigned short u[8]; } wk;
#pragma unroll
            for (int u = 0; u < 8; ++u) wk.u[u] = bfbits(kvv[u]);
            *(bf8_t*)(Ks + sk * 32 + sd) = wk.v;
#pragma unroll
            for (int u = 0; u < 8; ++u) {
                const int r = sd + u;
                Vt[r * 64 + (sk ^ ((r & 7) << 3))] = bfbits(vvv[u]);
            }
        }
        __syncthreads();

        // QK^T: 4 S^T tiles of 16 keys
        f4_t s[4];
#pragma unroll
        for (int tt = 0; tt < 4; ++tt) {
            const bf8_t kf = *(const bf8_t*)(Ks + (tt * 16 + c) * 32 + 8 * g);
            f4_t z = {0.f, 0.f, 0.f, 0.f};
            s[tt] = MFMA16(kf, qf, z);
        }
        float sv[16];
#pragma unroll
        for (int tt = 0; tt < 4; ++tt)
#pragma unroll
            for (int r = 0; r < 4; ++r) {
                float x = s[tt][r];
                if (kc + tt * 16 + 4 * g + r >= NQ_) x = -1e30f;
                sv[tt * 4 + r] = x;
            }
        float mloc = sv[0];
#pragma unroll
        for (int i = 1; i < 16; ++i) mloc = fmaxf(mloc, sv[i]);
        mloc = fmaxf(mloc, __shfl_xor(mloc, 16));
        mloc = fmaxf(mloc, __shfl_xor(mloc, 32));
        const float mnew = fmaxf(m_run, mloc);
        const float resc = __expf(m_run - mnew);
        float p[16], ls = 0.f;
#pragma unroll
        for (int i = 0; i < 16; ++i) { p[i] = __expf(sv[i] - mnew); ls += p[i]; }
        ls += __shfl_xor(ls, 16);
        ls += __shfl_xor(ls, 32);
        l_run = l_run * resc + ls;
        m_run = mnew;
#pragma unroll
        for (int r = 0; r < 4; ++r) { acc0[r] *= resc; acc1[r] *= resc; }

        // pack P to bf16 pairs: pk[tile][word], word0 = rows {0,1}, word1 = {2,3}
        unsigned pk[4][2];
#pragma unroll
        for (int tt = 0; tt < 4; ++tt) {
            pk[tt][0] = (unsigned)bfbits(p[tt * 4 + 0]) | ((unsigned)bfbits(p[tt * 4 + 1]) << 16);
            pk[tt][1] = (unsigned)bfbits(p[tt * 4 + 2]) | ((unsigned)bfbits(p[tt * 4 + 3]) << 16);
        }
        // PV over two 32-key halves
        const int srcA = ((g & 1) << 5) + c;
        const int srcB = srcA + 16;
#pragma unroll
        for (int kh = 0; kh < 2; ++kh) {
            const unsigned a0 = __shfl(pk[kh * 2][0], srcA), b0_ = __shfl(pk[kh * 2 + 1][0], srcA);
            const unsigned a1 = __shfl(pk[kh * 2][1], srcA), b1_ = __shfl(pk[kh * 2 + 1][1], srcA);
            const unsigned a2 = __shfl(pk[kh * 2][0], srcB), b2_ = __shfl(pk[kh * 2 + 1][0], srcB);
            const unsigned a3 = __shfl(pk[kh * 2][1], srcB), b3_ = __shfl(pk[kh * 2 + 1][1], srcB);
            union { bf8_t v; unsigned u[4]; } pf;
            const bool hi = (g & 2);
            pf.u[0] = hi ? b0_ : a0; pf.u[1] = hi ? b1_ : a1;
            pf.u[2] = hi ? b2_ : a2; pf.u[3] = hi ? b3_ : a3;
            const int kcol = (kh * 32 + 8 * g) ^ ((c & 7) << 3);
            const bf8_t vf0 = *(const bf8_t*)(Vt + c * 64 + kcol);
            const bf8_t vf1 = *(const bf8_t*)(Vt + (16 + c) * 64 + kcol);
            acc0 = MFMA16(vf0, pf.v, acc0);
            acc1 = MFMA16(vf1, pf.v, acc1);
        }
    }

    // writeback via LDS transpose (per-wave 528-float region)
    __syncthreads();
    const float invl = 1.f / l_run;
    float* O = smemf + wave * 528;
#pragma unroll
    for (int r = 0; r < 4; ++r) {
        O[c * 33 + 4 * g + r] = acc0[r] * invl;
        O[c * 33 + 16 + 4 * g + r] = acc1[r] * invl;
    }
    __syncthreads();
    {
        const int ql = lane >> 2, part = lane & 3;
        const int qg = q0 + ql;
        if (qg < NQ_) {
            float o[8];
#pragma unroll
            for (int u = 0; u < 8; ++u) o[u] = O[ql * 33 + part * 8 + u];
            float* op = sa + ((long)qg * BS_ + b) * D_ + h * HD_ + part * 8;
            *(float4*)op = make_float4(o[0], o[1], o[2], o[3]);
            *(float4*)(op + 4) = make_float4(o[4], o[5], o[6], o[7]);
        }
    }
}

// ---------------- msdeform: aw softmax + bilinear gather + weighted sum --------
__global__ __launch_bounds__(256) void msdeform_kernel(
    const float* __restrict__ awlog, const float* __restrict__ offb,
    const float* __restrict__ refp, const __hip_bfloat16* __restrict__ val,
    float* __restrict__ out)
{
    __shared__ float saw[128];
    __shared__ float redm[8], redi[8];
    __shared__ float swt[128][4];
    __shared__ int sidx[128][4];
    const int bq = blockIdx.x;
    const int b = bq / NQ_, q = bq % NQ_;
    const int t = threadIdx.x;
    if (t < 128) saw[t] = awlog[(long)bq * 128 + t];
    __syncthreads();
    if (t < 8) {
        float mx = -1e30f;
        for (int i = 0; i < 16; ++i) mx = fmaxf(mx, saw[t * 16 + i]);
        float s = 0.f;
        for (int i = 0; i < 16; ++i) s += __expf(saw[t * 16 + i] - mx);
        redm[t] = mx; redi[t] = 1.f / s;
    }
    __syncthreads();
    if (t < 128) {
        const int h = t >> 4, lp = t & 15, l = lp >> 2, p = lp & 3;
        const float aw = __expf(saw[t] - redm[h]) * redi[h];
        const int Wi = (l == 0) ? 100 : (l == 1) ? 50 : (l == 2) ? 25 : 13;
        const int Hi = Wi;
        const int sl = (l == 0) ? 0 : (l == 1) ? 10000 : (l == 2) ? 12500 : 13125;
        const float offx = offb[(long)bq * 256 + h * 32 + l * 8 + p * 2 + 0];
        const float offy = offb[(long)bq * 256 + h * 32 + l * 8 + p * 2 + 1];
        const float refx = refp[(((long)q * BS_ + b) * NL_ + l) * 2 + 0];
        const float refy = refp[(((long)q * BS_ + b) * NL_ + l) * 2 + 1];
        const float fW = (float)Wi, fH = (float)Hi;
        const float x = (refx + offx / fW) * fW - 0.5f;
        const float y = (refy + offy / fH) * fH - 0.5f;
        const float x0f = floorf(x), y0f = floorf(y);
        const float fx = x - x0f, fy = y - y0f;
        const int ix = (int)x0f, iy = (int)y0f;
        const float wts[4] = {(1.f - fx) * (1.f - fy), fx * (1.f - fy),
                              (1.f - fx) * fy,          fx * fy};
        const int xs[4] = {ix, ix + 1, ix, ix + 1};
        const int ys[4] = {iy, iy, iy + 1, iy + 1};
#pragma unroll
        for (int tap = 0; tap < 4; ++tap) {
            const bool valid = (xs[tap] >= 0) & (xs[tap] < Wi) & (ys[tap] >= 0) & (ys[tap] < Hi);
            const int xc = min(max(xs[tap], 0), Wi - 1);
            const int yc = min(max(ys[tap], 0), Hi - 1);
            swt[t][tap] = valid ? aw * wts[tap] : 0.f;
            sidx[t][tap] = b * LMEM_ + sl + yc * Wi + xc;
        }
    }
    __syncthreads();
    const int h = t >> 5, d = t & 31;
    float acc = 0.f;
    for (int i = 0; i < 16; ++i) {
        const int j = h * 16 + i;
#pragma unroll
        for (int tap = 0; tap < 4; ++tap) {
            const float wv = swt[j][tap];
            if (wv != 0.f)
                acc += wv * __bfloat162float(val[(long)sidx[j][tap] * D_ + h * HD_ + d]);
        }
    }
    out[(long)bq * D_ + h * HD_ + d] = acc;
}

// ---------------- LayerNorm ----------------
__global__ __launch_bounds__(256) void ln_kernel(
    const float* __restrict__ inA, const float* __restrict__ inB,
    const float* __restrict__ g, const float* __restrict__ be,
    float* __restrict__ out, const float* __restrict__ pos,
    float* __restrict__ extraOut, int swapB)
{
    const int r = blockIdx.x * 4 + (threadIdx.x >> 6);
    const int lane = threadIdx.x & 63;
    long rb = r;
    if (swapB) rb = (long)(r & 7) * NQ_ + (r >> 3);
    const float4 a4 = *(const float4*)(inA + (long)r * D_ + lane * 4);
    const float4 b4 = *(const float4*)(inB + rb * D_ + lane * 4);
    float x[4] = {a4.x + b4.x, a4.y + b4.y, a4.z + b4.z, a4.w + b4.w};
    float s = x[0] + x[1] + x[2] + x[3];
#pragma unroll
    for (int off = 32; off > 0; off >>= 1) s += __shfl_xor(s, off);
    const float mu = s * (1.f / D_);
    float v = 0.f;
#pragma unroll
    for (int c = 0; c < 4; ++c) { const float dd = x[c] - mu; v += dd * dd; }
#pragma unroll
    for (int off = 32; off > 0; off >>= 1) v += __shfl_xor(v, off);
    const float rs = rsqrtf(v * (1.f / D_) + 1e-5f);
    const float4 g4 = *(const float4*)(g + lane * 4);
    const float4 e4 = *(const float4*)(be + lane * 4);
    const float gg[4] = {g4.x, g4.y, g4.z, g4.w};
    const float ee[4] = {e4.x, e4.y, e4.z, e4.w};
    float y[4];
#pragma unroll
    for (int c = 0; c < 4; ++c) y[c] = (x[c] - mu) * rs * gg[c] + ee[c];
    *(float4*)(out + (long)r * D_ + lane * 4) = make_float4(y[0], y[1], y[2], y[3]);
    if (extraOut) {
        const float4 p4 = *(const float4*)(pos + (long)r * D_ + lane * 4);
        const long er = (long)(r & 7) * NQ_ + (r >> 3);
        *(float4*)(extraOut + er * D_ + lane * 4) =
            make_float4(y[0] + p4.x, y[1] + p4.y, y[2] + p4.z, y[3] + p4.w);
    }
}

// ---------------------------------------------------------------------------
extern "C" void kernel_launch(void* const* d_in, const int* in_sizes, int n_in,
                              void* d_out, int out_size, void* d_ws, size_t ws_size,
                              hipStream_t stream) {
    const float* tgt   = (const float*)d_in[0];
    const float* pos   = (const float*)d_in[1];
    const float* refp  = (const float*)d_in[2];
    const float* mem   = (const float*)d_in[3];
    const float* ipw   = (const float*)d_in[6];
    const float* ipb   = (const float*)d_in[7];
    const float* opw   = (const float*)d_in[8];
    const float* opb   = (const float*)d_in[9];
    const float* sow   = (const float*)d_in[10];
    const float* sob   = (const float*)d_in[11];
    const float* aww   = (const float*)d_in[12];
    const float* awb   = (const float*)d_in[13];
    const float* vpw   = (const float*)d_in[14];
    const float* vpb   = (const float*)d_in[15];
    const float* outpw = (const float*)d_in[16];
    const float* outpb = (const float*)d_in[17];
    const float* l1w   = (const float*)d_in[18];
    const float* l1b   = (const float*)d_in[19];
    const float* l2w   = (const float*)d_in[20];
    const float* l2b   = (const float*)d_in[21];
    const float* n1g = (const float*)d_in[22]; const float* n1be = (const float*)d_in[23];
    const float* n2g = (const float*)d_in[24]; const float* n2be = (const float*)d_in[25];
    const float* n3g = (const float*)d_in[26]; const float* n3be = (const float*)d_in[27];

    float* w = (float*)d_ws;
    float* qplus  = w;
    float* Qb     = w + T;
    float* Kb     = w + 2 * T;
    float* Vb     = w + 3 * T;
    float* sa     = w + 4 * T;
    float* saproj = w + 5 * T;
    float* t1     = w + 6 * T;
    float* qplus2 = w + 7 * T;
    float* offb   = w + 8 * T;
    float* sampo  = w + 9 * T;
    float* ca     = w + 10 * T;
    float* t2     = w + 11 * T;
    float* ffno   = w + 12 * T;
    float* awlog  = w + 13 * T;
    __hip_bfloat16* val = (__hip_bfloat16*)(w + 14 * T);
    float* ffnh   = w;  // aliases qplus/Qb/Kb/Vb (4T floats) — dead by FFN time

    const dim3 blk(256);
    const dim3 g_m(113, 4);

    add_vec4<<<1800, blk, 0, stream>>>(tgt, pos, qplus, (int)(T / 4));
    gemm_atb<false, false><<<g_m, blk, 0, stream>>>(qplus, ipw,               ipb,           Qb, MTOK, D_, D_, MTOK, 0, 1);
    gemm_atb<false, false><<<g_m, blk, 0, stream>>>(qplus, ipw + D_ * D_,     ipb + D_,      Kb, MTOK, D_, D_, MTOK, 0, 1);
    gemm_atb<false, false><<<g_m, blk, 0, stream>>>(tgt,   ipw + 2 * D_ * D_, ipb + 2 * D_,  Vb, MTOK, D_, D_, MTOK, 0, 1);
    attn_mfma<<<dim3(64, 15), blk, 0, stream>>>(Qb, Kb, Vb, sa);
    gemm_atb<false, false><<<g_m, blk, 0, stream>>>(sa, opw, opb, saproj, MTOK, D_, D_, MTOK, 0, 1);
    ln_kernel<<<1800, blk, 0, stream>>>(tgt, saproj, n2g, n2be, t1, pos, qplus2, 0);
    gemm_atb<false, true><<<dim3((BS_ * LMEM_ + 63) / 64, 4), blk, 0, stream>>>(
        mem, vpw, vpb, val, BS_ * LMEM_, D_, D_, LMEM_, 1, BS_);
    gemm_atb<false, false><<<g_m, blk, 0, stream>>>(qplus2, sow, sob, offb, MTOK, D_, D_, MTOK, 0, 1);
    gemm_atb<false, false><<<dim3(113, 2), blk, 0, stream>>>(qplus2, aww, awb, awlog, MTOK, 128, D_, MTOK, 0, 1);
    msdeform_kernel<<<7200, blk, 0, stream>>>(awlog, offb, refp, val, sampo);
    gemm_atb<false, false><<<g_m, blk, 0, stream>>>(sampo, outpw, outpb, ca, MTOK, D_, D_, MTOK, 0, 1);
    ln_kernel<<<1800, blk, 0, stream>>>(t1, ca, n1g, n1be, t2, nullptr, nullptr, 1);
    gemm_atb<true, false><<<dim3(113, 16), blk, 0, stream>>>(t2, l1w, l1b, ffnh, MTOK, DFF_, D_, MTOK, 0, 1);
    gemm_atb<false, false><<<g_m, blk, 0, stream>>>(ffnh, l2w, l2b, ffno, MTOK, D_, DFF_, MTOK, 0, 1);
    ln_kernel<<<1800, blk, 0, stream>>>(t2, ffno, n3g, n3be, (float*)d_out, nullptr, nullptr, 0);
}

// Round 3
// 359.536 us; speedup vs baseline: 2.5915x; 1.7387x over previous
//
#include <hip/hip_runtime.h>
#include <hip/hip_bf16.h>

// ---------------------------------------------------------------------------
// DeformableTransformerDecoderLayer on MI355X — round 2: all-bf16 MFMA GEMMs.
// m97-structure GEMM (128x128 tile, BK=32, global_load_lds w16, 4 waves).
// ---------------------------------------------------------------------------

namespace {
constexpr int D_ = 256;
constexpr int NQ_ = 900;
constexpr int BS_ = 8;
constexpr int NH_ = 8;
constexpr int HD_ = 32;
constexpr int DFF_ = 1024;
constexpr int MTOK = NQ_ * BS_;       // 7200
constexpr int LMEM_ = 13294;
constexpr long T = (long)MTOK * D_;   // 1843200
constexpr float QSC = 0.17677669529663687f;  // 1/sqrt(32)
}

typedef __attribute__((ext_vector_type(8))) short bf8_t;
typedef __attribute__((ext_vector_type(4))) float f4_t;

#define MFMA16(a, b, c) __builtin_amdgcn_mfma_f32_16x16x32_bf16((a), (b), (c), 0, 0, 0)

__device__ __forceinline__ unsigned short bfbits(float x) {
    union { __hip_bfloat16 h; unsigned short u; } cv;
    cv.h = __float2bfloat16(x);
    return cv.u;
}

__device__ __forceinline__ void gload16(const unsigned short* g, unsigned short* l) {
    __builtin_amdgcn_global_load_lds(
        (const __attribute__((address_space(1))) unsigned int*)(g),
        (__attribute__((address_space(3))) unsigned int*)(l), 16, 0, 0);
}

// ---------------- conversion kernels ----------------
__global__ void conv_bf16(const float* __restrict__ src, unsigned short* __restrict__ dst, long n4) {
    const long i = (long)blockIdx.x * blockDim.x + threadIdx.x;
    if (i < n4) {
        const float4 v = ((const float4*)src)[i];
        union { unsigned short u[4]; uint2 w; } pk;
        pk.u[0] = bfbits(v.x); pk.u[1] = bfbits(v.y); pk.u[2] = bfbits(v.z); pk.u[3] = bfbits(v.w);
        ((uint2*)dst)[i] = pk.w;
    }
}

__global__ void add_bf16(const float* __restrict__ a, const float* __restrict__ b,
                         unsigned short* __restrict__ dst, long n4) {
    const long i = (long)blockIdx.x * blockDim.x + threadIdx.x;
    if (i < n4) {
        const float4 av = ((const float4*)a)[i];
        const float4 bv = ((const float4*)b)[i];
        union { unsigned short u[4]; uint2 w; } pk;
        pk.u[0] = bfbits(av.x + bv.x); pk.u[1] = bfbits(av.y + bv.y);
        pk.u[2] = bfbits(av.z + bv.z); pk.u[3] = bfbits(av.w + bv.w);
        ((uint2*)dst)[i] = pk.w;
    }
}

// mem[i][b][d] (LMEM x 8 x 256 f32) -> dst[(b*LMEM+i)*256 + d] bf16
__global__ void permute_mem(const float* __restrict__ mem, unsigned short* __restrict__ dst) {
    const long idx = (long)blockIdx.x * 256 + threadIdx.x;  // float4 chunks
    const int d4 = (int)(idx & 63);
    const int b = (int)((idx >> 6) & 7);
    const long i = idx >> 9;
    const float4 v = ((const float4*)mem)[idx];
    union { unsigned short u[4]; uint2 w; } pk;
    pk.u[0] = bfbits(v.x); pk.u[1] = bfbits(v.y); pk.u[2] = bfbits(v.z); pk.u[3] = bfbits(v.w);
    *(uint2*)(dst + (((long)b * LMEM_ + i) * D_ + d4 * 4)) = pk.w;
}

// fused weight conversion; Wq segment scaled by QSC; bqs = ipb[0:256]*QSC
__global__ void conv_weights(
    const float* __restrict__ ipw, const float* __restrict__ opw,
    const float* __restrict__ sow, const float* __restrict__ aww,
    const float* __restrict__ vpw, const float* __restrict__ outpw,
    const float* __restrict__ l1w, const float* __restrict__ l2w,
    const float* __restrict__ ipb, unsigned short* __restrict__ Wbf,
    float* __restrict__ bqs)
{
    if (blockIdx.x == 0 && threadIdx.x < 64) {
#pragma unroll
        for (int j = 0; j < 4; ++j)
            bqs[threadIdx.x * 4 + j] = ipb[threadIdx.x * 4 + j] * QSC;
    }
    const long idx4 = (long)blockIdx.x * 256 + threadIdx.x;
    if (idx4 >= 253952) return;
    const long e = idx4 * 4;
    const float* src; long off; float sc = 1.f;
    if (e < 196608)      { src = ipw;   off = 0;      if (e < 65536) sc = QSC; }
    else if (e < 262144) { src = opw;   off = 196608; }
    else if (e < 327680) { src = sow;   off = 262144; }
    else if (e < 360448) { src = aww;   off = 327680; }
    else if (e < 425984) { src = vpw;   off = 360448; }
    else if (e < 491520) { src = outpw; off = 425984; }
    else if (e < 753664) { src = l1w;   off = 491520; }
    else                 { src = l2w;   off = 753664; }
    const float4 v = *(const float4*)(src + (e - off));
    union { unsigned short u[4]; uint2 w; } pk;
    pk.u[0] = bfbits(v.x * sc); pk.u[1] = bfbits(v.y * sc);
    pk.u[2] = bfbits(v.z * sc); pk.u[3] = bfbits(v.w * sc);
    *(uint2*)(Wbf + e) = pk.w;
}

// ---------------- bf16 MFMA GEMM: C[r,n] = A[r,:] . W[n,:] + bias[n] ----------
// A [M][K] bf16 (row clamp at M-1), W [N][K] bf16, N%128==0, K%32==0.
// 128x128 tile, BK=32, 4 waves (2x2), each wave 64x64 (4x4 frags of 16x16).
template<bool RELU, bool OUTBF16>
__global__ __launch_bounds__(256) void gemm_mfma(
    const unsigned short* __restrict__ A, const unsigned short* __restrict__ W,
    const float* __restrict__ bias, void* __restrict__ C, int M, int N, int K)
{
    __shared__ unsigned short As[128 * 32];
    __shared__ unsigned short Ws[128 * 32];
    const int t = threadIdx.x;
    const long m0 = (long)blockIdx.x * 128;
    const int n0 = blockIdx.y * 128;
    const int row0 = t >> 2, cg = t & 3;
    long ar0 = m0 + row0;        if (ar0 > M - 1) ar0 = M - 1;
    long ar1 = m0 + 64 + row0;   if (ar1 > M - 1) ar1 = M - 1;
    const unsigned short* ga0 = A + ar0 * K + cg * 8;
    const unsigned short* ga1 = A + ar1 * K + cg * 8;
    const unsigned short* gw0 = W + (long)(n0 + row0) * K + cg * 8;
    const unsigned short* gw1 = W + (long)(n0 + 64 + row0) * K + cg * 8;
    unsigned short* la0 = As + t * 8;
    unsigned short* la1 = As + 2048 + t * 8;
    unsigned short* lw0 = Ws + t * 8;
    unsigned short* lw1 = Ws + 2048 + t * 8;
    const int lane = t & 63, wave = t >> 6;
    const int c = lane & 15, g = lane >> 4;
    const int wr = wave >> 1, wc = wave & 1;
    f4_t acc[4][4];
#pragma unroll
    for (int i = 0; i < 4; ++i)
#pragma unroll
        for (int j = 0; j < 4; ++j)
            acc[i][j] = f4_t{0.f, 0.f, 0.f, 0.f};

    for (int kb = 0; kb < K; kb += 32) {
        gload16(ga0 + kb, la0);
        gload16(ga1 + kb, la1);
        gload16(gw0 + kb, lw0);
        gload16(gw1 + kb, lw1);
        __syncthreads();
        bf8_t af[4], bfr[4];
#pragma unroll
        for (int i = 0; i < 4; ++i) {
            af[i] = *(const bf8_t*)(As + (wr * 64 + i * 16 + c) * 32 + g * 8);
            bfr[i] = *(const bf8_t*)(Ws + (wc * 64 + i * 16 + c) * 32 + g * 8);
        }
#pragma unroll
        for (int i = 0; i < 4; ++i)
#pragma unroll
            for (int j = 0; j < 4; ++j)
                acc[i][j] = MFMA16(af[i], bfr[j], acc[i][j]);
        __syncthreads();
    }

#pragma unroll
    for (int i = 0; i < 4; ++i) {
        const long rbase = m0 + wr * 64 + i * 16 + 4 * g;
#pragma unroll
        for (int j = 0; j < 4; ++j) {
            const int col = n0 + wc * 64 + j * 16 + c;
            const float bv = bias[col];
#pragma unroll
            for (int r = 0; r < 4; ++r) {
                const long rr = rbase + r;
                if (rr < M) {
                    float v = acc[i][j][r] + bv;
                    if (RELU) v = fmaxf(v, 0.f);
                    if (OUTBF16) ((unsigned short*)C)[rr * N + col] = bfbits(v);
                    else         ((float*)C)[rr * N + col] = v;
                }
            }
        }
    }
}

// ---------------- MFMA flash attention (bf16 in/out, Q pre-scaled) ------------
__global__ __launch_bounds__(256) void attn_mfma(
    const unsigned short* __restrict__ Qb, const unsigned short* __restrict__ Kb,
    const unsigned short* __restrict__ Vb, unsigned short* __restrict__ sa)
{
    __shared__ float smemf[2112];   // 4KB Ks + 4KB Vt; reused as 4x528f O-stage
    unsigned short* Ks = (unsigned short*)smemf;            // [64][32]
    unsigned short* Vt = (unsigned short*)(smemf + 1024);   // [32][64] swizzled
    const int t = threadIdx.x;
    const int wave = t >> 6, lane = t & 63;
    const int g = lane >> 4, c = lane & 15;
    const int b = blockIdx.x >> 3, h = blockIdx.x & 7;
    const int q0 = blockIdx.y * 64 + wave * 16;
    const int q = q0 + c;
    const bool qv = q < NQ_;
    const bf8_t qf = *(const bf8_t*)(Qb + ((long)(qv ? q : 0) * BS_ + b) * D_ + h * HD_ + 8 * g);

    f4_t acc0 = {0.f, 0.f, 0.f, 0.f}, acc1 = {0.f, 0.f, 0.f, 0.f};
    float m_run = -1e30f, l_run = 0.f;
    const int sk = t >> 2, sd = (t & 3) * 8;

    for (int kc = 0; kc < NQ_; kc += 64) {
        __syncthreads();
        {
            const int key = kc + sk;
            union { bf8_t v; unsigned short u[8]; } kv, vv;
            if (key < NQ_) {
                kv.v = *(const bf8_t*)(Kb + ((long)key * BS_ + b) * D_ + h * HD_ + sd);
                vv.v = *(const bf8_t*)(Vb + ((long)key * BS_ + b) * D_ + h * HD_ + sd);
            } else {
#pragma unroll
                for (int u = 0; u < 8; ++u) { kv.u[u] = 0; vv.u[u] = 0; }
            }
            *(bf8_t*)(Ks + sk * 32 + sd) = kv.v;
#pragma unroll
            for (int u = 0; u < 8; ++u) {
                const int r = sd + u;
                Vt[r * 64 + (sk ^ ((r & 7) << 3))] = vv.u[u];
            }
        }
        __syncthreads();

        f4_t s[4];
#pragma unroll
        for (int tt = 0; tt < 4; ++tt) {
            const bf8_t kf = *(const bf8_t*)(Ks + (tt * 16 + c) * 32 + 8 * g);
            f4_t z = {0.f, 0.f, 0.f, 0.f};
            s[tt] = MFMA16(kf, qf, z);
        }
        float sv[16];
#pragma unroll
        for (int tt = 0; tt < 4; ++tt)
#pragma unroll
            for (int r = 0; r < 4; ++r) {
                float x = s[tt][r];
                if (kc + tt * 16 + 4 * g + r >= NQ_) x = -1e30f;
                sv[tt * 4 + r] = x;
            }
        float mloc = sv[0];
#pragma unroll
        for (int i = 1; i < 16; ++i) mloc = fmaxf(mloc, sv[i]);
        mloc = fmaxf(mloc, __shfl_xor(mloc, 16));
        mloc = fmaxf(mloc, __shfl_xor(mloc, 32));
        const float mnew = fmaxf(m_run, mloc);
        const float resc = __expf(m_run - mnew);
        float p[16], ls = 0.f;
#pragma unroll
        for (int i = 0; i < 16; ++i) { p[i] = __expf(sv[i] - mnew); ls += p[i]; }
        ls += __shfl_xor(ls, 16);
        ls += __shfl_xor(ls, 32);
        l_run = l_run * resc + ls;
        m_run = mnew;
#pragma unroll
        for (int r = 0; r < 4; ++r) { acc0[r] *= resc; acc1[r] *= resc; }

        unsigned pk[4][2];
#pragma unroll
        for (int tt = 0; tt < 4; ++tt) {
            pk[tt][0] = (unsigned)bfbits(p[tt * 4 + 0]) | ((unsigned)bfbits(p[tt * 4 + 1]) << 16);
            pk[tt][1] = (unsigned)bfbits(p[tt * 4 + 2]) | ((unsigned)bfbits(p[tt * 4 + 3]) << 16);
        }
        const int srcA = ((g & 1) << 5) + c;
        const int srcB = srcA + 16;
#pragma unroll
        for (int kh = 0; kh < 2; ++kh) {
            const unsigned a0 = __shfl(pk[kh * 2][0], srcA), b0_ = __shfl(pk[kh * 2 + 1][0], srcA);
            const unsigned a1 = __shfl(pk[kh * 2][1], srcA), b1_ = __shfl(pk[kh * 2 + 1][1], srcA);
            const unsigned a2 = __shfl(pk[kh * 2][0], srcB), b2_ = __shfl(pk[kh * 2 + 1][0], srcB);
            const unsigned a3 = __shfl(pk[kh * 2][1], srcB), b3_ = __shfl(pk[kh * 2 + 1][1], srcB);
            union { bf8_t v; unsigned u[4]; } pf;
            const bool hi = (g & 2);
            pf.u[0] = hi ? b0_ : a0; pf.u[1] = hi ? b1_ : a1;
            pf.u[2] = hi ? b2_ : a2; pf.u[3] = hi ? b3_ : a3;
            const int kcol = (kh * 32 + 8 * g) ^ ((c & 7) << 3);
            const bf8_t vf0 = *(const bf8_t*)(Vt + c * 64 + kcol);
            const bf8_t vf1 = *(const bf8_t*)(Vt + (16 + c) * 64 + kcol);
            acc0 = MFMA16(vf0, pf.v, acc0);
            acc1 = MFMA16(vf1, pf.v, acc1);
        }
    }

    __syncthreads();
    const float invl = 1.f / l_run;
    float* O = smemf + wave * 528;
#pragma unroll
    for (int r = 0; r < 4; ++r) {
        O[c * 33 + 4 * g + r] = acc0[r] * invl;
        O[c * 33 + 16 + 4 * g + r] = acc1[r] * invl;
    }
    __syncthreads();
    {
        const int ql = lane >> 2, part = lane & 3;
        const int qg = q0 + ql;
        if (qg < NQ_) {
            union { bf8_t v; unsigned short u[8]; } pk;
#pragma unroll
            for (int u = 0; u < 8; ++u) pk.u[u] = bfbits(O[ql * 33 + part * 8 + u]);
            *(bf8_t*)(sa + ((long)qg * BS_ + b) * D_ + h * HD_ + part * 8) = pk.v;
        }
    }
}

// ---------------- msdeform: aw softmax + bilinear gather + weighted sum --------
__global__ __launch_bounds__(256) void msdeform_kernel(
    const float* __restrict__ awlog, const float* __restrict__ offb,
    const float* __restrict__ refp, const __hip_bfloat16* __restrict__ val,
    unsigned short* __restrict__ out)
{
    __shared__ float saw[128];
    __shared__ float redm[8], redi[8];
    __shared__ float swt[128][4];
    __shared__ int sidx[128][4];
    const int bq = blockIdx.x;
    const int b = bq / NQ_, q = bq % NQ_;
    const int t = threadIdx.x;
    if (t < 128) saw[t] = awlog[(long)bq * 128 + t];
    __syncthreads();
    if (t < 8) {
        float mx = -1e30f;
        for (int i = 0; i < 16; ++i) mx = fmaxf(mx, saw[t * 16 + i]);
        float s = 0.f;
        for (int i = 0; i < 16; ++i) s += __expf(saw[t * 16 + i] - mx);
        redm[t] = mx; redi[t] = 1.f / s;
    }
    __syncthreads();
    if (t < 128) {
        const int h = t >> 4, lp = t & 15, l = lp >> 2, p = lp & 3;
        const float aw = __expf(saw[t] - redm[h]) * redi[h];
        const int Wi = (l == 0) ? 100 : (l == 1) ? 50 : (l == 2) ? 25 : 13;
        const int Hi = Wi;
        const int sl = (l == 0) ? 0 : (l == 1) ? 10000 : (l == 2) ? 12500 : 13125;
        const float offx = offb[(long)bq * 256 + h * 32 + l * 8 + p * 2 + 0];
        const float offy = offb[(long)bq * 256 + h * 32 + l * 8 + p * 2 + 1];
        const float refx = refp[(((long)q * BS_ + b) * 4 + l) * 2 + 0];
        const float refy = refp[(((long)q * BS_ + b) * 4 + l) * 2 + 1];
        const float fW = (float)Wi, fH = (float)Hi;
        const float x = (refx + offx / fW) * fW - 0.5f;
        const float y = (refy + offy / fH) * fH - 0.5f;
        const float x0f = floorf(x), y0f = floorf(y);
        const float fx = x - x0f, fy = y - y0f;
        const int ix = (int)x0f, iy = (int)y0f;
        const float wts[4] = {(1.f - fx) * (1.f - fy), fx * (1.f - fy),
                              (1.f - fx) * fy,          fx * fy};
        const int xs[4] = {ix, ix + 1, ix, ix + 1};
        const int ys[4] = {iy, iy, iy + 1, iy + 1};
#pragma unroll
        for (int tap = 0; tap < 4; ++tap) {
            const bool valid = (xs[tap] >= 0) & (xs[tap] < Wi) & (ys[tap] >= 0) & (ys[tap] < Hi);
            const int xc = min(max(xs[tap], 0), Wi - 1);
            const int yc = min(max(ys[tap], 0), Hi - 1);
            swt[t][tap] = valid ? aw * wts[tap] : 0.f;
            sidx[t][tap] = b * LMEM_ + sl + yc * Wi + xc;
        }
    }
    __syncthreads();
    const int h = t >> 5, d = t & 31;
    float acc = 0.f;
    for (int i = 0; i < 16; ++i) {
        const int j = h * 16 + i;
#pragma unroll
        for (int tap = 0; tap < 4; ++tap) {
            const float wv = swt[j][tap];
            if (wv != 0.f)
                acc += wv * __bfloat162float(val[(long)sidx[j][tap] * D_ + h * HD_ + d]);
        }
    }
    out[(long)bq * D_ + h * HD_ + d] = bfbits(acc);
}

// ---------------- LayerNorm: out = LN(inA[r] + inB[rb]); optional bf16 out ----
// swapB: rb = (r&7)*NQ + (r>>3).  bfMode: 0 none, 1 plain y, 2 transposed y+pos.
__global__ __launch_bounds__(256) void ln_kernel(
    const float* __restrict__ inA, const float* __restrict__ inB,
    const float* __restrict__ g, const float* __restrict__ be,
    float* __restrict__ out, const float* __restrict__ pos,
    unsigned short* __restrict__ bfOut, int swapB, int bfMode)
{
    const int r = blockIdx.x * 4 + (threadIdx.x >> 6);
    const int lane = threadIdx.x & 63;
    long rb = r;
    if (swapB) rb = (long)(r & 7) * NQ_ + (r >> 3);
    const float4 a4 = *(const float4*)(inA + (long)r * D_ + lane * 4);
    const float4 b4 = *(const float4*)(inB + rb * D_ + lane * 4);
    float x[4] = {a4.x + b4.x, a4.y + b4.y, a4.z + b4.z, a4.w + b4.w};
    float s = x[0] + x[1] + x[2] + x[3];
#pragma unroll
    for (int off = 32; off > 0; off >>= 1) s += __shfl_xor(s, off);
    const float mu = s * (1.f / D_);
    float v = 0.f;
#pragma unroll
    for (int cc = 0; cc < 4; ++cc) { const float dd = x[cc] - mu; v += dd * dd; }
#pragma unroll
    for (int off = 32; off > 0; off >>= 1) v += __shfl_xor(v, off);
    const float rs = rsqrtf(v * (1.f / D_) + 1e-5f);
    const float4 g4 = *(const float4*)(g + lane * 4);
    const float4 e4 = *(const float4*)(be + lane * 4);
    const float gg[4] = {g4.x, g4.y, g4.z, g4.w};
    const float ee[4] = {e4.x, e4.y, e4.z, e4.w};
    float y[4];
#pragma unroll
    for (int cc = 0; cc < 4; ++cc) y[cc] = (x[cc] - mu) * rs * gg[cc] + ee[cc];
    *(float4*)(out + (long)r * D_ + lane * 4) = make_float4(y[0], y[1], y[2], y[3]);
    if (bfMode) {
        float z[4] = {y[0], y[1], y[2], y[3]};
        long er = r;
        if (bfMode == 2) {
            const float4 p4 = *(const float4*)(pos + (long)r * D_ + lane * 4);
            z[0] += p4.x; z[1] += p4.y; z[2] += p4.z; z[3] += p4.w;
            er = (long)(r & 7) * NQ_ + (r >> 3);
        }
        union { unsigned short u[4]; uint2 w; } pk;
        pk.u[0] = bfbits(z[0]); pk.u[1] = bfbits(z[1]);
        pk.u[2] = bfbits(z[2]); pk.u[3] = bfbits(z[3]);
        *(uint2*)(bfOut + er * D_ + lane * 4) = pk.w;
    }
}

// ---------------------------------------------------------------------------
extern "C" void kernel_launch(void* const* d_in, const int* in_sizes, int n_in,
                              void* d_out, int out_size, void* d_ws, size_t ws_size,
                              hipStream_t stream) {
    const float* tgt   = (const float*)d_in[0];
    const float* pos   = (const float*)d_in[1];
    const float* refp  = (const float*)d_in[2];
    const float* mem   = (const float*)d_in[3];
    const float* ipw   = (const float*)d_in[6];
    const float* ipb   = (const float*)d_in[7];
    const float* opw   = (const float*)d_in[8];
    const float* opb   = (const float*)d_in[9];
    const float* sow   = (const float*)d_in[10];
    const float* sob   = (const float*)d_in[11];
    const float* aww   = (const float*)d_in[12];
    const float* awb   = (const float*)d_in[13];
    const float* vpw   = (const float*)d_in[14];
    const float* vpb   = (const float*)d_in[15];
    const float* outpw = (const float*)d_in[16];
    const float* outpb = (const float*)d_in[17];
    const float* l1w   = (const float*)d_in[18];
    const float* l1b   = (const float*)d_in[19];
    const float* l2w   = (const float*)d_in[20];
    const float* l2b   = (const float*)d_in[21];
    const float* n1g = (const float*)d_in[22]; const float* n1be = (const float*)d_in[23];
    const float* n2g = (const float*)d_in[24]; const float* n2be = (const float*)d_in[25];
    const float* n3g = (const float*)d_in[26]; const float* n3be = (const float*)d_in[27];

    // ---- workspace carve-up (all regions 256B aligned) ----
    char* wsb = (char*)d_ws;
    auto alloc = [&](size_t bytes) { char* p = wsb; wsb += (bytes + 255) & ~(size_t)255; return p; };
    unsigned short* Wbf      = (unsigned short*)alloc(1015808 * 2);
    float*          bqs      = (float*)alloc(256 * 4);
    unsigned short* tgt_bf   = (unsigned short*)alloc(T * 2);   // later: sampo_bf
    unsigned short* qplus_bf = (unsigned short*)alloc(T * 2);   // later: qplus2_bf
    unsigned short* Qb_bf    = (unsigned short*)alloc(T * 2);   // later: t2_bf
    unsigned short* Kb_bf    = (unsigned short*)alloc(T * 2);   // later: t2 (f32, spans Kb+Vb)
    unsigned short* Vb_bf    = (unsigned short*)alloc(T * 2);
    unsigned short* sa_bf    = (unsigned short*)alloc(T * 2);   // later: awlog (f32)
    float*          saproj   = (float*)alloc(T * 4);            // later: offb
    float*          t1       = (float*)alloc(T * 4);
    unsigned short* memT     = (unsigned short*)alloc((long)BS_ * LMEM_ * D_ * 2); // later: ffnh/ffno/ca
    unsigned short* val      = (unsigned short*)alloc((long)BS_ * LMEM_ * D_ * 2);
    // aliases (non-overlapping lifetimes)
    unsigned short* qplus2_bf = qplus_bf;
    unsigned short* sampo_bf  = tgt_bf;
    float*          awlog     = (float*)sa_bf;
    float*          offb      = saproj;
    float*          t2        = (float*)Kb_bf;
    unsigned short* t2_bf     = Qb_bf;
    unsigned short* ffnh_bf   = memT;
    float*          ffno      = (float*)((char*)memT + (long)MTOK * DFF_ * 2);
    float*          ca        = (float*)((char*)ffno + T * 4);
    // weight slices inside Wbf
    const unsigned short* wq  = Wbf + 0;
    const unsigned short* wk  = Wbf + 65536;
    const unsigned short* wv  = Wbf + 131072;
    const unsigned short* wo  = Wbf + 196608;
    const unsigned short* wso = Wbf + 262144;
    const unsigned short* waw = Wbf + 327680;
    const unsigned short* wvp = Wbf + 360448;
    const unsigned short* wop = Wbf + 425984;
    const unsigned short* wl1 = Wbf + 491520;
    const unsigned short* wl2 = Wbf + 753664;

    const dim3 blk(256);
    const dim3 g_m(57, 2);   // 7200 rows, 256 cols

    // conversions
    conv_weights<<<992, blk, 0, stream>>>(ipw, opw, sow, aww, vpw, outpw, l1w, l2w, ipb, Wbf, bqs);
    conv_bf16<<<1800, blk, 0, stream>>>(tgt, tgt_bf, T / 4);
    add_bf16<<<1800, blk, 0, stream>>>(tgt, pos, qplus_bf, T / 4);
    permute_mem<<<26588, blk, 0, stream>>>(mem, memT);
    // QKV projections
    gemm_mfma<false, true><<<g_m, blk, 0, stream>>>(qplus_bf, wq, bqs,       Qb_bf, MTOK, D_, D_);
    gemm_mfma<false, true><<<g_m, blk, 0, stream>>>(qplus_bf, wk, ipb + D_,  Kb_bf, MTOK, D_, D_);
    gemm_mfma<false, true><<<g_m, blk, 0, stream>>>(tgt_bf,   wv, ipb + 2*D_, Vb_bf, MTOK, D_, D_);
    // self-attention
    attn_mfma<<<dim3(64, 15), blk, 0, stream>>>(Qb_bf, Kb_bf, Vb_bf, sa_bf);
    // out_proj
    gemm_mfma<false, false><<<g_m, blk, 0, stream>>>(sa_bf, wo, opb, saproj, MTOK, D_, D_);
    // t1 = LN2(tgt + saproj); qplus2_bf = bf16(t1 + pos) transposed (b,q)
    ln_kernel<<<1800, blk, 0, stream>>>(tgt, saproj, n2g, n2be, t1, pos, qplus2_bf, 0, 2);
    // value projection
    gemm_mfma<false, true><<<dim3(831, 2), blk, 0, stream>>>(memT, wvp, vpb, val, BS_ * LMEM_, D_, D_);
    // sampling offsets + attention-weight logits
    gemm_mfma<false, false><<<g_m, blk, 0, stream>>>(qplus2_bf, wso, sob, offb, MTOK, D_, D_);
    gemm_mfma<false, false><<<dim3(57, 1), blk, 0, stream>>>(qplus2_bf, waw, awb, awlog, MTOK, 128, D_);
    // deformable sampling
    msdeform_kernel<<<7200, blk, 0, stream>>>(awlog, offb, refp, (const __hip_bfloat16*)val, sampo_bf);
    // output projection
    gemm_mfma<false, false><<<g_m, blk, 0, stream>>>(sampo_bf, wop, outpb, ca, MTOK, D_, D_);
    // t2 = LN1(t1 + ca^T) + bf16 copy
    ln_kernel<<<1800, blk, 0, stream>>>(t1, ca, n1g, n1be, t2, nullptr, t2_bf, 1, 1);
    // FFN
    gemm_mfma<true, true><<<dim3(57, 8), blk, 0, stream>>>(t2_bf, wl1, l1b, ffnh_bf, MTOK, DFF_, D_);
    gemm_mfma<false, false><<<g_m, blk, 0, stream>>>(ffnh_bf, wl2, l2b, ffno, MTOK, D_, DFF_);
    // out = LN3(t2 + ffn)
    ln_kernel<<<1800, blk, 0, stream>>>(t2, ffno, n3g, n3be, (float*)d_out, nullptr, nullptr, 0, 0);
}

// Round 4
// 272.930 us; speedup vs baseline: 3.4139x; 1.3173x over previous
//
#include <hip/hip_runtime.h>
#include <hip/hip_bf16.h>

// ---------------------------------------------------------------------------
// DeformableTransformerDecoderLayer on MI355X — round 3:
//  - msdeform gather rewritten: 8B/lane uint2 loads, tap-parallel lanes
//  - fused QK projection (N=512) and samp_off+attn_w (N=384) GEMMs
//  - prep_inputs fuses tgt->bf16 and (tgt+pos)->bf16
// ---------------------------------------------------------------------------

namespace {
constexpr int D_ = 256;
constexpr int NQ_ = 900;
constexpr int BS_ = 8;
constexpr int NH_ = 8;
constexpr int HD_ = 32;
constexpr int DFF_ = 1024;
constexpr int MTOK = NQ_ * BS_;       // 7200
constexpr int LMEM_ = 13294;
constexpr long T = (long)MTOK * D_;   // 1843200
constexpr float QSC = 0.17677669529663687f;  // 1/sqrt(32)
constexpr int QKS = 512;              // fused QK row stride
}

typedef __attribute__((ext_vector_type(8))) short bf8_t;
typedef __attribute__((ext_vector_type(4))) float f4_t;

#define MFMA16(a, b, c) __builtin_amdgcn_mfma_f32_16x16x32_bf16((a), (b), (c), 0, 0, 0)

__device__ __forceinline__ unsigned short bfbits(float x) {
    union { __hip_bfloat16 h; unsigned short u; } cv;
    cv.h = __float2bfloat16(x);
    return cv.u;
}
__device__ __forceinline__ float bf2f(unsigned short u) {
    union { float f; unsigned v; } cv;
    cv.v = ((unsigned)u) << 16;
    return cv.f;
}

__device__ __forceinline__ void gload16(const unsigned short* g, unsigned short* l) {
    __builtin_amdgcn_global_load_lds(
        (const __attribute__((address_space(1))) unsigned int*)(g),
        (__attribute__((address_space(3))) unsigned int*)(l), 16, 0, 0);
}

// ---------------- prep: tgt_bf = bf16(tgt); qplus_bf = bf16(tgt+pos) ----------
__global__ void prep_inputs(const float* __restrict__ tgt, const float* __restrict__ pos,
                            unsigned short* __restrict__ tgt_bf,
                            unsigned short* __restrict__ qplus_bf, long n4) {
    const long i = (long)blockIdx.x * blockDim.x + threadIdx.x;
    if (i < n4) {
        const float4 tv = ((const float4*)tgt)[i];
        const float4 pv = ((const float4*)pos)[i];
        union { unsigned short u[4]; uint2 w; } a, b;
        a.u[0] = bfbits(tv.x); a.u[1] = bfbits(tv.y); a.u[2] = bfbits(tv.z); a.u[3] = bfbits(tv.w);
        b.u[0] = bfbits(tv.x + pv.x); b.u[1] = bfbits(tv.y + pv.y);
        b.u[2] = bfbits(tv.z + pv.z); b.u[3] = bfbits(tv.w + pv.w);
        ((uint2*)tgt_bf)[i] = a.w;
        ((uint2*)qplus_bf)[i] = b.w;
    }
}

// mem[i][b][d] (LMEM x 8 x 256 f32) -> dst[(b*LMEM+i)*256 + d] bf16
__global__ void permute_mem(const float* __restrict__ mem, unsigned short* __restrict__ dst) {
    const long idx = (long)blockIdx.x * 256 + threadIdx.x;  // float4 chunks
    const int d4 = (int)(idx & 63);
    const int b = (int)((idx >> 6) & 7);
    const long i = idx >> 9;
    const float4 v = ((const float4*)mem)[idx];
    union { unsigned short u[4]; uint2 w; } pk;
    pk.u[0] = bfbits(v.x); pk.u[1] = bfbits(v.y); pk.u[2] = bfbits(v.z); pk.u[3] = bfbits(v.w);
    *(uint2*)(dst + (((long)b * LMEM_ + i) * D_ + d4 * 4)) = pk.w;
}

// fused weight conversion; Wq scaled by QSC; biasAll = [qk bias 512 | oa bias 384]
__global__ void conv_weights(
    const float* __restrict__ ipw, const float* __restrict__ opw,
    const float* __restrict__ sow, const float* __restrict__ aww,
    const float* __restrict__ vpw, const float* __restrict__ outpw,
    const float* __restrict__ l1w, const float* __restrict__ l2w,
    const float* __restrict__ ipb, const float* __restrict__ sob,
    const float* __restrict__ awb,
    unsigned short* __restrict__ Wbf, float* __restrict__ biasAll)
{
    if (blockIdx.x == 0) {
        for (int j = threadIdx.x; j < 512; j += 256)
            biasAll[j] = (j < 256) ? ipb[j] * QSC : ipb[j];
        for (int j = threadIdx.x; j < 384; j += 256)
            biasAll[512 + j] = (j < 256) ? sob[j] : awb[j - 256];
    }
    const long idx4 = (long)blockIdx.x * 256 + threadIdx.x;
    if (idx4 >= 253952) return;
    const long e = idx4 * 4;
    const float* src; long off; float sc = 1.f;
    if (e < 196608)      { src = ipw;   off = 0;      if (e < 65536) sc = QSC; }
    else if (e < 262144) { src = opw;   off = 196608; }
    else if (e < 327680) { src = sow;   off = 262144; }
    else if (e < 360448) { src = aww;   off = 327680; }
    else if (e < 425984) { src = vpw;   off = 360448; }
    else if (e < 491520) { src = outpw; off = 425984; }
    else if (e < 753664) { src = l1w;   off = 491520; }
    else                 { src = l2w;   off = 753664; }
    const float4 v = *(const float4*)(src + (e - off));
    union { unsigned short u[4]; uint2 w; } pk;
    pk.u[0] = bfbits(v.x * sc); pk.u[1] = bfbits(v.y * sc);
    pk.u[2] = bfbits(v.z * sc); pk.u[3] = bfbits(v.w * sc);
    *(uint2*)(Wbf + e) = pk.w;
}

// ---------------- bf16 MFMA GEMM: C[r,n] = A[r,:] . W[n,:] + bias[n] ----------
template<bool RELU, bool OUTBF16>
__global__ __launch_bounds__(256) void gemm_mfma(
    const unsigned short* __restrict__ A, const unsigned short* __restrict__ W,
    const float* __restrict__ bias, void* __restrict__ C, int M, int N, int K)
{
    __shared__ unsigned short As[128 * 32];
    __shared__ unsigned short Ws[128 * 32];
    const int t = threadIdx.x;
    const long m0 = (long)blockIdx.x * 128;
    const int n0 = blockIdx.y * 128;
    const int row0 = t >> 2, cg = t & 3;
    long ar0 = m0 + row0;        if (ar0 > M - 1) ar0 = M - 1;
    long ar1 = m0 + 64 + row0;   if (ar1 > M - 1) ar1 = M - 1;
    const unsigned short* ga0 = A + ar0 * K + cg * 8;
    const unsigned short* ga1 = A + ar1 * K + cg * 8;
    const unsigned short* gw0 = W + (long)(n0 + row0) * K + cg * 8;
    const unsigned short* gw1 = W + (long)(n0 + 64 + row0) * K + cg * 8;
    unsigned short* la0 = As + t * 8;
    unsigned short* la1 = As + 2048 + t * 8;
    unsigned short* lw0 = Ws + t * 8;
    unsigned short* lw1 = Ws + 2048 + t * 8;
    const int lane = t & 63, wave = t >> 6;
    const int c = lane & 15, g = lane >> 4;
    const int wr = wave >> 1, wc = wave & 1;
    f4_t acc[4][4];
#pragma unroll
    for (int i = 0; i < 4; ++i)
#pragma unroll
        for (int j = 0; j < 4; ++j)
            acc[i][j] = f4_t{0.f, 0.f, 0.f, 0.f};

    for (int kb = 0; kb < K; kb += 32) {
        gload16(ga0 + kb, la0);
        gload16(ga1 + kb, la1);
        gload16(gw0 + kb, lw0);
        gload16(gw1 + kb, lw1);
        __syncthreads();
        bf8_t af[4], bfr[4];
#pragma unroll
        for (int i = 0; i < 4; ++i) {
            af[i] = *(const bf8_t*)(As + (wr * 64 + i * 16 + c) * 32 + g * 8);
            bfr[i] = *(const bf8_t*)(Ws + (wc * 64 + i * 16 + c) * 32 + g * 8);
        }
#pragma unroll
        for (int i = 0; i < 4; ++i)
#pragma unroll
            for (int j = 0; j < 4; ++j)
                acc[i][j] = MFMA16(af[i], bfr[j], acc[i][j]);
        __syncthreads();
    }

#pragma unroll
    for (int i = 0; i < 4; ++i) {
        const long rbase = m0 + wr * 64 + i * 16 + 4 * g;
#pragma unroll
        for (int j = 0; j < 4; ++j) {
            const int col = n0 + wc * 64 + j * 16 + c;
            const float bv = bias[col];
#pragma unroll
            for (int r = 0; r < 4; ++r) {
                const long rr = rbase + r;
                if (rr < M) {
                    float v = acc[i][j][r] + bv;
                    if (RELU) v = fmaxf(v, 0.f);
                    if (OUTBF16) ((unsigned short*)C)[rr * N + col] = bfbits(v);
                    else         ((float*)C)[rr * N + col] = v;
                }
            }
        }
    }
}

// ---------------- MFMA flash attention (Q/K fused rows of 512) ----------------
__global__ __launch_bounds__(256) void attn_mfma(
    const unsigned short* __restrict__ Qb, const unsigned short* __restrict__ Kb,
    const unsigned short* __restrict__ Vb, unsigned short* __restrict__ sa)
{
    __shared__ float smemf[2112];   // 4KB Ks + 4KB Vt; reused as 4x528f O-stage
    unsigned short* Ks = (unsigned short*)smemf;            // [64][32]
    unsigned short* Vt = (unsigned short*)(smemf + 1024);   // [32][64] swizzled
    const int t = threadIdx.x;
    const int wave = t >> 6, lane = t & 63;
    const int g = lane >> 4, c = lane & 15;
    const int b = blockIdx.x >> 3, h = blockIdx.x & 7;
    const int q0 = blockIdx.y * 64 + wave * 16;
    const int q = q0 + c;
    const bool qv = q < NQ_;
    const bf8_t qf = *(const bf8_t*)(Qb + ((long)(qv ? q : 0) * BS_ + b) * QKS + h * HD_ + 8 * g);

    f4_t acc0 = {0.f, 0.f, 0.f, 0.f}, acc1 = {0.f, 0.f, 0.f, 0.f};
    float m_run = -1e30f, l_run = 0.f;
    const int sk = t >> 2, sd = (t & 3) * 8;

    for (int kc = 0; kc < NQ_; kc += 64) {
        __syncthreads();
        {
            const int key = kc + sk;
            union { bf8_t v; unsigned short u[8]; } kv, vv;
            if (key < NQ_) {
                kv.v = *(const bf8_t*)(Kb + ((long)key * BS_ + b) * QKS + h * HD_ + sd);
                vv.v = *(const bf8_t*)(Vb + ((long)key * BS_ + b) * D_ + h * HD_ + sd);
            } else {
#pragma unroll
                for (int u = 0; u < 8; ++u) { kv.u[u] = 0; vv.u[u] = 0; }
            }
            *(bf8_t*)(Ks + sk * 32 + sd) = kv.v;
#pragma unroll
            for (int u = 0; u < 8; ++u) {
                const int r = sd + u;
                Vt[r * 64 + (sk ^ ((r & 7) << 3))] = vv.u[u];
            }
        }
        __syncthreads();

        f4_t s[4];
#pragma unroll
        for (int tt = 0; tt < 4; ++tt) {
            const bf8_t kf = *(const bf8_t*)(Ks + (tt * 16 + c) * 32 + 8 * g);
            f4_t z = {0.f, 0.f, 0.f, 0.f};
            s[tt] = MFMA16(kf, qf, z);
        }
        float sv[16];
#pragma unroll
        for (int tt = 0; tt < 4; ++tt)
#pragma unroll
            for (int r = 0; r < 4; ++r) {
                float x = s[tt][r];
                if (kc + tt * 16 + 4 * g + r >= NQ_) x = -1e30f;
                sv[tt * 4 + r] = x;
            }
        float mloc = sv[0];
#pragma unroll
        for (int i = 1; i < 16; ++i) mloc = fmaxf(mloc, sv[i]);
        mloc = fmaxf(mloc, __shfl_xor(mloc, 16));
        mloc = fmaxf(mloc, __shfl_xor(mloc, 32));
        const float mnew = fmaxf(m_run, mloc);
        const float resc = __expf(m_run - mnew);
        float p[16], ls = 0.f;
#pragma unroll
        for (int i = 0; i < 16; ++i) { p[i] = __expf(sv[i] - mnew); ls += p[i]; }
        ls += __shfl_xor(ls, 16);
        ls += __shfl_xor(ls, 32);
        l_run = l_run * resc + ls;
        m_run = mnew;
#pragma unroll
        for (int r = 0; r < 4; ++r) { acc0[r] *= resc; acc1[r] *= resc; }

        unsigned pk[4][2];
#pragma unroll
        for (int tt = 0; tt < 4; ++tt) {
            pk[tt][0] = (unsigned)bfbits(p[tt * 4 + 0]) | ((unsigned)bfbits(p[tt * 4 + 1]) << 16);
            pk[tt][1] = (unsigned)bfbits(p[tt * 4 + 2]) | ((unsigned)bfbits(p[tt * 4 + 3]) << 16);
        }
        const int srcA = ((g & 1) << 5) + c;
        const int srcB = srcA + 16;
#pragma unroll
        for (int kh = 0; kh < 2; ++kh) {
            const unsigned a0 = __shfl(pk[kh * 2][0], srcA), b0_ = __shfl(pk[kh * 2 + 1][0], srcA);
            const unsigned a1 = __shfl(pk[kh * 2][1], srcA), b1_ = __shfl(pk[kh * 2 + 1][1], srcA);
            const unsigned a2 = __shfl(pk[kh * 2][0], srcB), b2_ = __shfl(pk[kh * 2 + 1][0], srcB);
            const unsigned a3 = __shfl(pk[kh * 2][1], srcB), b3_ = __shfl(pk[kh * 2 + 1][1], srcB);
            union { bf8_t v; unsigned u[4]; } pf;
            const bool hi = (g & 2);
            pf.u[0] = hi ? b0_ : a0; pf.u[1] = hi ? b1_ : a1;
            pf.u[2] = hi ? b2_ : a2; pf.u[3] = hi ? b3_ : a3;
            const int kcol = (kh * 32 + 8 * g) ^ ((c & 7) << 3);
            const bf8_t vf0 = *(const bf8_t*)(Vt + c * 64 + kcol);
            const bf8_t vf1 = *(const bf8_t*)(Vt + (16 + c) * 64 + kcol);
            acc0 = MFMA16(vf0, pf.v, acc0);
            acc1 = MFMA16(vf1, pf.v, acc1);
        }
    }

    __syncthreads();
    const float invl = 1.f / l_run;
    float* O = smemf + wave * 528;
#pragma unroll
    for (int r = 0; r < 4; ++r) {
        O[c * 33 + 4 * g + r] = acc0[r] * invl;
        O[c * 33 + 16 + 4 * g + r] = acc1[r] * invl;
    }
    __syncthreads();
    {
        const int ql = lane >> 2, part = lane & 3;
        const int qg = q0 + ql;
        if (qg < NQ_) {
            union { bf8_t v; unsigned short u[8]; } pk;
#pragma unroll
            for (int u = 0; u < 8; ++u) pk.u[u] = bfbits(O[ql * 33 + part * 8 + u]);
            *(bf8_t*)(sa + ((long)qg * BS_ + b) * D_ + h * HD_ + part * 8) = pk.v;
        }
    }
}

// ---------------- msdeform: softmax + bilinear gather (8B/lane) ----------------
// oa rows of 384: cols 0-255 = sampling offsets, 256-383 = attn-weight logits.
__global__ __launch_bounds__(256) void msdeform_kernel(
    const float* __restrict__ oa, const float* __restrict__ refp,
    const unsigned short* __restrict__ val, unsigned short* __restrict__ out)
{
    __shared__ float saw[128];
    __shared__ float redm[8], redi[8];
    __shared__ float swt[128][4];
    __shared__ int sidx[128][4];
    const int bq = blockIdx.x;
    const int b = bq / NQ_, q = bq % NQ_;
    const int t = threadIdx.x;
    if (t < 128) saw[t] = oa[(long)bq * 384 + 256 + t];
    __syncthreads();
    if (t < 8) {
        float mx = -1e30f;
        for (int i = 0; i < 16; ++i) mx = fmaxf(mx, saw[t * 16 + i]);
        float s = 0.f;
        for (int i = 0; i < 16; ++i) s += __expf(saw[t * 16 + i] - mx);
        redm[t] = mx; redi[t] = 1.f / s;
    }
    __syncthreads();
    if (t < 128) {
        const int h = t >> 4, lp = t & 15, l = lp >> 2, p = lp & 3;
        const float aw = __expf(saw[t] - redm[h]) * redi[h];
        const int Wi = (l == 0) ? 100 : (l == 1) ? 50 : (l == 2) ? 25 : 13;
        const int Hi = Wi;
        const int sl = (l == 0) ? 0 : (l == 1) ? 10000 : (l == 2) ? 12500 : 13125;
        const float offx = oa[(long)bq * 384 + h * 32 + l * 8 + p * 2 + 0];
        const float offy = oa[(long)bq * 384 + h * 32 + l * 8 + p * 2 + 1];
        const float refx = refp[(((long)q * BS_ + b) * 4 + l) * 2 + 0];
        const float refy = refp[(((long)q * BS_ + b) * 4 + l) * 2 + 1];
        const float fW = (float)Wi, fH = (float)Hi;
        const float x = (refx + offx / fW) * fW - 0.5f;
        const float y = (refy + offy / fH) * fH - 0.5f;
        const float x0f = floorf(x), y0f = floorf(y);
        const float fx = x - x0f, fy = y - y0f;
        const int ix = (int)x0f, iy = (int)y0f;
        const float wts[4] = {(1.f - fx) * (1.f - fy), fx * (1.f - fy),
                              (1.f - fx) * fy,          fx * fy};
        const int xs[4] = {ix, ix + 1, ix, ix + 1};
        const int ys[4] = {iy, iy, iy + 1, iy + 1};
#pragma unroll
        for (int tap = 0; tap < 4; ++tap) {
            const bool valid = (xs[tap] >= 0) & (xs[tap] < Wi) & (ys[tap] >= 0) & (ys[tap] < Hi);
            const int xc = min(max(xs[tap], 0), Wi - 1);
            const int yc = min(max(ys[tap], 0), Hi - 1);
            swt[t][tap] = valid ? aw * wts[tap] : 0.f;
            sidx[t][tap] = b * LMEM_ + sl + yc * Wi + xc;
        }
    }
    __syncthreads();
    // gather: h = head, qd = channel quad (4 ch), s = tap slot
    const int h = t >> 5, r = t & 31, qd = r & 7, s = r >> 3;
    float a0 = 0.f, a1 = 0.f, a2 = 0.f, a3 = 0.f;
#pragma unroll
    for (int i = 0; i < 16; ++i) {
        const int j = h * 16 + i;
        const float wv = swt[j][s];
        const long base = (long)sidx[j][s] * D_ + h * HD_ + qd * 4;
        const uint2 raw = *(const uint2*)(val + base);
        a0 += wv * bf2f((unsigned short)(raw.x & 0xffff));
        a1 += wv * bf2f((unsigned short)(raw.x >> 16));
        a2 += wv * bf2f((unsigned short)(raw.y & 0xffff));
        a3 += wv * bf2f((unsigned short)(raw.y >> 16));
    }
    a0 += __shfl_xor(a0, 8); a0 += __shfl_xor(a0, 16);
    a1 += __shfl_xor(a1, 8); a1 += __shfl_xor(a1, 16);
    a2 += __shfl_xor(a2, 8); a2 += __shfl_xor(a2, 16);
    a3 += __shfl_xor(a3, 8); a3 += __shfl_xor(a3, 16);
    if (s == 0) {
        union { unsigned short u[4]; uint2 w; } pk;
        pk.u[0] = bfbits(a0); pk.u[1] = bfbits(a1); pk.u[2] = bfbits(a2); pk.u[3] = bfbits(a3);
        *(uint2*)(out + (long)bq * D_ + h * HD_ + qd * 4) = pk.w;
    }
}

// ---------------- LayerNorm: out = LN(inA[r] + inB[rb]); optional bf16 out ----
__global__ __launch_bounds__(256) void ln_kernel(
    const float* __restrict__ inA, const float* __restrict__ inB,
    const float* __restrict__ g, const float* __restrict__ be,
    float* __restrict__ out, const float* __restrict__ pos,
    unsigned short* __restrict__ bfOut, int swapB, int bfMode)
{
    const int r = blockIdx.x * 4 + (threadIdx.x >> 6);
    const int lane = threadIdx.x & 63;
    long rb = r;
    if (swapB) rb = (long)(r & 7) * NQ_ + (r >> 3);
    const float4 a4 = *(const float4*)(inA + (long)r * D_ + lane * 4);
    const float4 b4 = *(const float4*)(inB + rb * D_ + lane * 4);
    float x[4] = {a4.x + b4.x, a4.y + b4.y, a4.z + b4.z, a4.w + b4.w};
    float s = x[0] + x[1] + x[2] + x[3];
#pragma unroll
    for (int off = 32; off > 0; off >>= 1) s += __shfl_xor(s, off);
    const float mu = s * (1.f / D_);
    float v = 0.f;
#pragma unroll
    for (int cc = 0; cc < 4; ++cc) { const float dd = x[cc] - mu; v += dd * dd; }
#pragma unroll
    for (int off = 32; off > 0; off >>= 1) v += __shfl_xor(v, off);
    const float rs = rsqrtf(v * (1.f / D_) + 1e-5f);
    const float4 g4 = *(const float4*)(g + lane * 4);
    const float4 e4 = *(const float4*)(be + lane * 4);
    const float gg[4] = {g4.x, g4.y, g4.z, g4.w};
    const float ee[4] = {e4.x, e4.y, e4.z, e4.w};
    float y[4];
#pragma unroll
    for (int cc = 0; cc < 4; ++cc) y[cc] = (x[cc] - mu) * rs * gg[cc] + ee[cc];
    *(float4*)(out + (long)r * D_ + lane * 4) = make_float4(y[0], y[1], y[2], y[3]);
    if (bfMode) {
        float z[4] = {y[0], y[1], y[2], y[3]};
        long er = r;
        if (bfMode == 2) {
            const float4 p4 = *(const float4*)(pos + (long)r * D_ + lane * 4);
            z[0] += p4.x; z[1] += p4.y; z[2] += p4.z; z[3] += p4.w;
            er = (long)(r & 7) * NQ_ + (r >> 3);
        }
        union { unsigned short u[4]; uint2 w; } pk;
        pk.u[0] = bfbits(z[0]); pk.u[1] = bfbits(z[1]);
        pk.u[2] = bfbits(z[2]); pk.u[3] = bfbits(z[3]);
        *(uint2*)(bfOut + er * D_ + lane * 4) = pk.w;
    }
}

// ---------------------------------------------------------------------------
extern "C" void kernel_launch(void* const* d_in, const int* in_sizes, int n_in,
                              void* d_out, int out_size, void* d_ws, size_t ws_size,
                              hipStream_t stream) {
    const float* tgt   = (const float*)d_in[0];
    const float* pos   = (const float*)d_in[1];
    const float* refp  = (const float*)d_in[2];
    const float* mem   = (const float*)d_in[3];
    const float* ipw   = (const float*)d_in[6];
    const float* ipb   = (const float*)d_in[7];
    const float* opw   = (const float*)d_in[8];
    const float* opb   = (const float*)d_in[9];
    const float* sow   = (const float*)d_in[10];
    const float* sob   = (const float*)d_in[11];
    const float* aww   = (const float*)d_in[12];
    const float* awb   = (const float*)d_in[13];
    const float* vpw   = (const float*)d_in[14];
    const float* vpb   = (const float*)d_in[15];
    const float* outpw = (const float*)d_in[16];
    const float* outpb = (const float*)d_in[17];
    const float* l1w   = (const float*)d_in[18];
    const float* l1b   = (const float*)d_in[19];
    const float* l2w   = (const float*)d_in[20];
    const float* l2b   = (const float*)d_in[21];
    const float* n1g = (const float*)d_in[22]; const float* n1be = (const float*)d_in[23];
    const float* n2g = (const float*)d_in[24]; const float* n2be = (const float*)d_in[25];
    const float* n3g = (const float*)d_in[26]; const float* n3be = (const float*)d_in[27];

    // ---- workspace carve-up (all regions 256B aligned) ----
    char* wsb = (char*)d_ws;
    auto alloc = [&](size_t bytes) { char* p = wsb; wsb += (bytes + 255) & ~(size_t)255; return p; };
    unsigned short* Wbf      = (unsigned short*)alloc(1015808 * 2);
    float*          biasAll  = (float*)alloc(896 * 4);
    unsigned short* tgt_bf   = (unsigned short*)alloc(T * 2);   // later: sampo_bf
    unsigned short* qplus_bf = (unsigned short*)alloc(T * 2);   // later: qplus2_bf
    unsigned short* QK_bf    = (unsigned short*)alloc(T * 4);   // Q|K fused; later: t2_bf / t2
    unsigned short* Vb_bf    = (unsigned short*)alloc(T * 2);   // later: t2 upper half
    unsigned short* sa_bf    = (unsigned short*)alloc(T * 2);   // later: oa (with saproj)
    float*          saproj   = (float*)alloc(T * 4);
    float*          t1       = (float*)alloc(T * 4);
    unsigned short* memT     = (unsigned short*)alloc((long)BS_ * LMEM_ * D_ * 2); // later: ffnh/ffno/ca
    unsigned short* val      = (unsigned short*)alloc((long)BS_ * LMEM_ * D_ * 2);
    // aliases (non-overlapping lifetimes)
    unsigned short* qplus2_bf = qplus_bf;
    unsigned short* sampo_bf  = tgt_bf;
    float*          oa        = (float*)sa_bf;  // spans sa_bf(2T)+saproj(4T) = 7200*384 f32
    float*          t2        = (float*)(QK_bf + T);  // spans K-half(2T)+Vb(2T) bytes
    unsigned short* t2_bf     = QK_bf;                // Q-half, dead after attn
    unsigned short* ffnh_bf   = memT;
    float*          ffno      = (float*)((char*)memT + (long)MTOK * DFF_ * 2);
    float*          ca        = (float*)((char*)ffno + T * 4);
    // weight slices inside Wbf
    const unsigned short* wqk = Wbf + 0;        // 512 x 256
    const unsigned short* wv  = Wbf + 131072;
    const unsigned short* wo  = Wbf + 196608;
    const unsigned short* wsoaw = Wbf + 262144; // 384 x 256
    const unsigned short* wvp = Wbf + 360448;
    const unsigned short* wop = Wbf + 425984;
    const unsigned short* wl1 = Wbf + 491520;
    const unsigned short* wl2 = Wbf + 753664;
    const float* bias_qk = biasAll;
    const float* bias_oa = biasAll + 512;

    const dim3 blk(256);
    const dim3 g_m(57, 2);   // 7200 rows, 256 cols

    conv_weights<<<992, blk, 0, stream>>>(ipw, opw, sow, aww, vpw, outpw, l1w, l2w,
                                          ipb, sob, awb, Wbf, biasAll);
    prep_inputs<<<1800, blk, 0, stream>>>(tgt, pos, tgt_bf, qplus_bf, T / 4);
    permute_mem<<<26588, blk, 0, stream>>>(mem, memT);
    // fused QK projection (N=512)
    gemm_mfma<false, true><<<dim3(57, 4), blk, 0, stream>>>(qplus_bf, wqk, bias_qk, QK_bf, MTOK, QKS, D_);
    // V projection
    gemm_mfma<false, true><<<g_m, blk, 0, stream>>>(tgt_bf, wv, ipb + 2 * D_, Vb_bf, MTOK, D_, D_);
    // self-attention
    attn_mfma<<<dim3(64, 15), blk, 0, stream>>>(QK_bf, QK_bf + 256, Vb_bf, sa_bf);
    // out_proj
    gemm_mfma<false, false><<<g_m, blk, 0, stream>>>(sa_bf, wo, opb, saproj, MTOK, D_, D_);
    // t1 = LN2(tgt + saproj); qplus2_bf = bf16(t1 + pos) transposed (b,q)
    ln_kernel<<<1800, blk, 0, stream>>>(tgt, saproj, n2g, n2be, t1, pos, qplus2_bf, 0, 2);
    // value projection
    gemm_mfma<false, true><<<dim3(831, 2), blk, 0, stream>>>(memT, wvp, vpb, val, BS_ * LMEM_, D_, D_);
    // fused samp_off + attn_w (N=384, f32 out)
    gemm_mfma<false, false><<<dim3(57, 3), blk, 0, stream>>>(qplus2_bf, wsoaw, bias_oa, oa, MTOK, 384, D_);
    // deformable sampling
    msdeform_kernel<<<7200, blk, 0, stream>>>(oa, refp, val, sampo_bf);
    // output projection
    gemm_mfma<false, false><<<g_m, blk, 0, stream>>>(sampo_bf, wop, outpb, ca, MTOK, D_, D_);
    // t2 = LN1(t1 + ca^T) + bf16 copy
    ln_kernel<<<1800, blk, 0, stream>>>(t1, ca, n1g, n1be, t2, nullptr, t2_bf, 1, 1);
    // FFN
    gemm_mfma<true, true><<<dim3(57, 8), blk, 0, stream>>>(t2_bf, wl1, l1b, ffnh_bf, MTOK, DFF_, D_);
    gemm_mfma<false, false><<<g_m, blk, 0, stream>>>(ffnh_bf, wl2, l2b, ffno, MTOK, D_, DFF_);
    // out = LN3(t2 + ffn)
    ln_kernel<<<1800, blk, 0, stream>>>(t2, ffno, n3g, n3be, (float*)d_out, nullptr, nullptr, 0, 0);
}

// Round 5
// 258.487 us; speedup vs baseline: 3.6046x; 1.0559x over previous
//
#include <hip/hip_runtime.h>
#include <hip/hip_bf16.h>

// ---------------------------------------------------------------------------
// DeformableTransformerDecoderLayer on MI355X — round 4:
//  - gemm_f32a: fp32-A GEMM variant with in-staging bf16 convert, row remap,
//    optional fused add. Kills permute_mem + prep_inputs (≈220MB HBM traffic).
//  - no workspace aliasing (ws is large).
// ---------------------------------------------------------------------------

namespace {
constexpr int D_ = 256;
constexpr int NQ_ = 900;
constexpr int BS_ = 8;
constexpr int NH_ = 8;
constexpr int HD_ = 32;
constexpr int DFF_ = 1024;
constexpr int MTOK = NQ_ * BS_;       // 7200
constexpr int LMEM_ = 13294;
constexpr long T = (long)MTOK * D_;   // 1843200
constexpr float QSC = 0.17677669529663687f;  // 1/sqrt(32)
constexpr int QKS = 512;              // fused QK row stride
}

typedef __attribute__((ext_vector_type(8))) short bf8_t;
typedef __attribute__((ext_vector_type(4))) float f4_t;

#define MFMA16(a, b, c) __builtin_amdgcn_mfma_f32_16x16x32_bf16((a), (b), (c), 0, 0, 0)

__device__ __forceinline__ unsigned short bfbits(float x) {
    union { __hip_bfloat16 h; unsigned short u; } cv;
    cv.h = __float2bfloat16(x);
    return cv.u;
}
__device__ __forceinline__ float bf2f(unsigned short u) {
    union { float f; unsigned v; } cv;
    cv.v = ((unsigned)u) << 16;
    return cv.f;
}

__device__ __forceinline__ void gload16(const unsigned short* g, unsigned short* l) {
    __builtin_amdgcn_global_load_lds(
        (const __attribute__((address_space(1))) unsigned int*)(g),
        (__attribute__((address_space(3))) unsigned int*)(l), 16, 0, 0);
}

// fused weight conversion; Wq scaled by QSC; biasAll = [qk bias 512 | oa bias 384]
__global__ void conv_weights(
    const float* __restrict__ ipw, const float* __restrict__ opw,
    const float* __restrict__ sow, const float* __restrict__ aww,
    const float* __restrict__ vpw, const float* __restrict__ outpw,
    const float* __restrict__ l1w, const float* __restrict__ l2w,
    const float* __restrict__ ipb, const float* __restrict__ sob,
    const float* __restrict__ awb,
    unsigned short* __restrict__ Wbf, float* __restrict__ biasAll)
{
    if (blockIdx.x == 0) {
        for (int j = threadIdx.x; j < 512; j += 256)
            biasAll[j] = (j < 256) ? ipb[j] * QSC : ipb[j];
        for (int j = threadIdx.x; j < 384; j += 256)
            biasAll[512 + j] = (j < 256) ? sob[j] : awb[j - 256];
    }
    const long idx4 = (long)blockIdx.x * 256 + threadIdx.x;
    if (idx4 >= 253952) return;
    const long e = idx4 * 4;
    const float* src; long off; float sc = 1.f;
    if (e < 196608)      { src = ipw;   off = 0;      if (e < 65536) sc = QSC; }
    else if (e < 262144) { src = opw;   off = 196608; }
    else if (e < 327680) { src = sow;   off = 262144; }
    else if (e < 360448) { src = aww;   off = 327680; }
    else if (e < 425984) { src = vpw;   off = 360448; }
    else if (e < 491520) { src = outpw; off = 425984; }
    else if (e < 753664) { src = l1w;   off = 491520; }
    else                 { src = l2w;   off = 753664; }
    const float4 v = *(const float4*)(src + (e - off));
    union { unsigned short u[4]; uint2 w; } pk;
    pk.u[0] = bfbits(v.x * sc); pk.u[1] = bfbits(v.y * sc);
    pk.u[2] = bfbits(v.z * sc); pk.u[3] = bfbits(v.w * sc);
    *(uint2*)(Wbf + e) = pk.w;
}

// ---------------- bf16-A MFMA GEMM: C[r,n] = A[r,:] . W[n,:] + bias[n] --------
template<bool RELU, bool OUTBF16>
__global__ __launch_bounds__(256) void gemm_mfma(
    const unsigned short* __restrict__ A, const unsigned short* __restrict__ W,
    const float* __restrict__ bias, void* __restrict__ C, int M, int N, int K)
{
    __shared__ unsigned short As[128 * 32];
    __shared__ unsigned short Ws[128 * 32];
    const int t = threadIdx.x;
    const long m0 = (long)blockIdx.x * 128;
    const int n0 = blockIdx.y * 128;
    const int row0 = t >> 2, cg = t & 3;
    long ar0 = m0 + row0;        if (ar0 > M - 1) ar0 = M - 1;
    long ar1 = m0 + 64 + row0;   if (ar1 > M - 1) ar1 = M - 1;
    const unsigned short* ga0 = A + ar0 * K + cg * 8;
    const unsigned short* ga1 = A + ar1 * K + cg * 8;
    const unsigned short* gw0 = W + (long)(n0 + row0) * K + cg * 8;
    const unsigned short* gw1 = W + (long)(n0 + 64 + row0) * K + cg * 8;
    unsigned short* la0 = As + t * 8;
    unsigned short* la1 = As + 2048 + t * 8;
    unsigned short* lw0 = Ws + t * 8;
    unsigned short* lw1 = Ws + 2048 + t * 8;
    const int lane = t & 63, wave = t >> 6;
    const int c = lane & 15, g = lane >> 4;
    const int wr = wave >> 1, wc = wave & 1;
    f4_t acc[4][4];
#pragma unroll
    for (int i = 0; i < 4; ++i)
#pragma unroll
        for (int j = 0; j < 4; ++j)
            acc[i][j] = f4_t{0.f, 0.f, 0.f, 0.f};

    for (int kb = 0; kb < K; kb += 32) {
        gload16(ga0 + kb, la0);
        gload16(ga1 + kb, la1);
        gload16(gw0 + kb, lw0);
        gload16(gw1 + kb, lw1);
        __syncthreads();
        bf8_t af[4], bfr[4];
#pragma unroll
        for (int i = 0; i < 4; ++i) {
            af[i] = *(const bf8_t*)(As + (wr * 64 + i * 16 + c) * 32 + g * 8);
            bfr[i] = *(const bf8_t*)(Ws + (wc * 64 + i * 16 + c) * 32 + g * 8);
        }
#pragma unroll
        for (int i = 0; i < 4; ++i)
#pragma unroll
            for (int j = 0; j < 4; ++j)
                acc[i][j] = MFMA16(af[i], bfr[j], acc[i][j]);
        __syncthreads();
    }

#pragma unroll
    for (int i = 0; i < 4; ++i) {
        const long rbase = m0 + wr * 64 + i * 16 + 4 * g;
#pragma unroll
        for (int j = 0; j < 4; ++j) {
            const int col = n0 + wc * 64 + j * 16 + c;
            const float bv = bias[col];
#pragma unroll
            for (int r = 0; r < 4; ++r) {
                const long rr = rbase + r;
                if (rr < M) {
                    float v = acc[i][j][r] + bv;
                    if (RELU) v = fmaxf(v, 0.f);
                    if (OUTBF16) ((unsigned short*)C)[rr * N + col] = bfbits(v);
                    else         ((float*)C)[rr * N + col] = v;
                }
            }
        }
    }
}

// ---------------- fp32-A MFMA GEMM with row remap + optional fused add --------
// arow(r) = (r/R1)*S1 + (r%R1)*S2;  A2 (if non-null) added, indexed by arow too.
template<bool OUTBF16>
__global__ __launch_bounds__(256) void gemm_f32a(
    const float* __restrict__ A, const float* __restrict__ A2,
    const unsigned short* __restrict__ W, const float* __restrict__ bias,
    void* __restrict__ C, int M, int N, int K, int R1, int S1, int S2)
{
    __shared__ unsigned short As[128 * 32];
    __shared__ unsigned short Ws[128 * 32];
    const int t = threadIdx.x;
    const long m0 = (long)blockIdx.x * 128;
    const int n0 = blockIdx.y * 128;
    const int row0 = t >> 2, cg = t & 3;
    int gr0 = (int)m0 + row0;       if (gr0 > M - 1) gr0 = M - 1;
    int gr1 = (int)m0 + 64 + row0;  if (gr1 > M - 1) gr1 = M - 1;
    const long ar0 = (long)(gr0 / R1) * S1 + (long)(gr0 % R1) * S2;
    const long ar1 = (long)(gr1 / R1) * S1 + (long)(gr1 % R1) * S2;
    const float* Ap0 = A + ar0 * K + cg * 8;
    const float* Ap1 = A + ar1 * K + cg * 8;
    const float* Bp0 = A2 ? A2 + ar0 * K + cg * 8 : nullptr;
    const float* Bp1 = A2 ? A2 + ar1 * K + cg * 8 : nullptr;
    const unsigned short* gw0 = W + (long)(n0 + row0) * K + cg * 8;
    const unsigned short* gw1 = W + (long)(n0 + 64 + row0) * K + cg * 8;
    unsigned short* la0 = As + row0 * 32 + cg * 8;
    unsigned short* la1 = As + (64 + row0) * 32 + cg * 8;
    unsigned short* lw0 = Ws + t * 8;
    unsigned short* lw1 = Ws + 2048 + t * 8;
    const int lane = t & 63, wave = t >> 6;
    const int c = lane & 15, g = lane >> 4;
    const int wr = wave >> 1, wc = wave & 1;
    f4_t acc[4][4];
#pragma unroll
    for (int i = 0; i < 4; ++i)
#pragma unroll
        for (int j = 0; j < 4; ++j)
            acc[i][j] = f4_t{0.f, 0.f, 0.f, 0.f};

    for (int kb = 0; kb < K; kb += 32) {
        gload16(gw0 + kb, lw0);
        gload16(gw1 + kb, lw1);
        float4 a00 = *(const float4*)(Ap0 + kb);
        float4 a01 = *(const float4*)(Ap0 + kb + 4);
        float4 a10 = *(const float4*)(Ap1 + kb);
        float4 a11 = *(const float4*)(Ap1 + kb + 4);
        if (A2) {
            const float4 b00 = *(const float4*)(Bp0 + kb);
            const float4 b01 = *(const float4*)(Bp0 + kb + 4);
            const float4 b10 = *(const float4*)(Bp1 + kb);
            const float4 b11 = *(const float4*)(Bp1 + kb + 4);
            a00.x += b00.x; a00.y += b00.y; a00.z += b00.z; a00.w += b00.w;
            a01.x += b01.x; a01.y += b01.y; a01.z += b01.z; a01.w += b01.w;
            a10.x += b10.x; a10.y += b10.y; a10.z += b10.z; a10.w += b10.w;
            a11.x += b11.x; a11.y += b11.y; a11.z += b11.z; a11.w += b11.w;
        }
        union { bf8_t v; unsigned short u[8]; } p0, p1;
        p0.u[0] = bfbits(a00.x); p0.u[1] = bfbits(a00.y); p0.u[2] = bfbits(a00.z); p0.u[3] = bfbits(a00.w);
        p0.u[4] = bfbits(a01.x); p0.u[5] = bfbits(a01.y); p0.u[6] = bfbits(a01.z); p0.u[7] = bfbits(a01.w);
        p1.u[0] = bfbits(a10.x); p1.u[1] = bfbits(a10.y); p1.u[2] = bfbits(a10.z); p1.u[3] = bfbits(a10.w);
        p1.u[4] = bfbits(a11.x); p1.u[5] = bfbits(a11.y); p1.u[6] = bfbits(a11.z); p1.u[7] = bfbits(a11.w);
        *(bf8_t*)la0 = p0.v;
        *(bf8_t*)la1 = p1.v;
        __syncthreads();
        bf8_t af[4], bfr[4];
#pragma unroll
        for (int i = 0; i < 4; ++i) {
            af[i] = *(const bf8_t*)(As + (wr * 64 + i * 16 + c) * 32 + g * 8);
            bfr[i] = *(const bf8_t*)(Ws + (wc * 64 + i * 16 + c) * 32 + g * 8);
        }
#pragma unroll
        for (int i = 0; i < 4; ++i)
#pragma unroll
            for (int j = 0; j < 4; ++j)
                acc[i][j] = MFMA16(af[i], bfr[j], acc[i][j]);
        __syncthreads();
    }

#pragma unroll
    for (int i = 0; i < 4; ++i) {
        const long rbase = m0 + wr * 64 + i * 16 + 4 * g;
#pragma unroll
        for (int j = 0; j < 4; ++j) {
            const int col = n0 + wc * 64 + j * 16 + c;
            const float bv = bias[col];
#pragma unroll
            for (int r = 0; r < 4; ++r) {
                const long rr = rbase + r;
                if (rr < M) {
                    float v = acc[i][j][r] + bv;
                    if (OUTBF16) ((unsigned short*)C)[rr * N + col] = bfbits(v);
                    else         ((float*)C)[rr * N + col] = v;
                }
            }
        }
    }
}

// ---------------- MFMA flash attention (Q/K fused rows of 512) ----------------
__global__ __launch_bounds__(256) void attn_mfma(
    const unsigned short* __restrict__ Qb, const unsigned short* __restrict__ Kb,
    const unsigned short* __restrict__ Vb, unsigned short* __restrict__ sa)
{
    __shared__ float smemf[2112];   // 4KB Ks + 4KB Vt; reused as 4x528f O-stage
    unsigned short* Ks = (unsigned short*)smemf;            // [64][32]
    unsigned short* Vt = (unsigned short*)(smemf + 1024);   // [32][64] swizzled
    const int t = threadIdx.x;
    const int wave = t >> 6, lane = t & 63;
    const int g = lane >> 4, c = lane & 15;
    const int b = blockIdx.x >> 3, h = blockIdx.x & 7;
    const int q0 = blockIdx.y * 64 + wave * 16;
    const int q = q0 + c;
    const bool qv = q < NQ_;
    const bf8_t qf = *(const bf8_t*)(Qb + ((long)(qv ? q : 0) * BS_ + b) * QKS + h * HD_ + 8 * g);

    f4_t acc0 = {0.f, 0.f, 0.f, 0.f}, acc1 = {0.f, 0.f, 0.f, 0.f};
    float m_run = -1e30f, l_run = 0.f;
    const int sk = t >> 2, sd = (t & 3) * 8;

    for (int kc = 0; kc < NQ_; kc += 64) {
        __syncthreads();
        {
            const int key = kc + sk;
            union { bf8_t v; unsigned short u[8]; } kv, vv;
            if (key < NQ_) {
                kv.v = *(const bf8_t*)(Kb + ((long)key * BS_ + b) * QKS + h * HD_ + sd);
                vv.v = *(const bf8_t*)(Vb + ((long)key * BS_ + b) * D_ + h * HD_ + sd);
            } else {
#pragma unroll
                for (int u = 0; u < 8; ++u) { kv.u[u] = 0; vv.u[u] = 0; }
            }
            *(bf8_t*)(Ks + sk * 32 + sd) = kv.v;
#pragma unroll
            for (int u = 0; u < 8; ++u) {
                const int r = sd + u;
                Vt[r * 64 + (sk ^ ((r & 7) << 3))] = vv.u[u];
            }
        }
        __syncthreads();

        f4_t s[4];
#pragma unroll
        for (int tt = 0; tt < 4; ++tt) {
            const bf8_t kf = *(const bf8_t*)(Ks + (tt * 16 + c) * 32 + 8 * g);
            f4_t z = {0.f, 0.f, 0.f, 0.f};
            s[tt] = MFMA16(kf, qf, z);
        }
        float sv[16];
#pragma unroll
        for (int tt = 0; tt < 4; ++tt)
#pragma unroll
            for (int r = 0; r < 4; ++r) {
                float x = s[tt][r];
                if (kc + tt * 16 + 4 * g + r >= NQ_) x = -1e30f;
                sv[tt * 4 + r] = x;
            }
        float mloc = sv[0];
#pragma unroll
        for (int i = 1; i < 16; ++i) mloc = fmaxf(mloc, sv[i]);
        mloc = fmaxf(mloc, __shfl_xor(mloc, 16));
        mloc = fmaxf(mloc, __shfl_xor(mloc, 32));
        const float mnew = fmaxf(m_run, mloc);
        const float resc = __expf(m_run - mnew);
        float p[16], ls = 0.f;
#pragma unroll
        for (int i = 0; i < 16; ++i) { p[i] = __expf(sv[i] - mnew); ls += p[i]; }
        ls += __shfl_xor(ls, 16);
        ls += __shfl_xor(ls, 32);
        l_run = l_run * resc + ls;
        m_run = mnew;
#pragma unroll
        for (int r = 0; r < 4; ++r) { acc0[r] *= resc; acc1[r] *= resc; }

        unsigned pk[4][2];
#pragma unroll
        for (int tt = 0; tt < 4; ++tt) {
            pk[tt][0] = (unsigned)bfbits(p[tt * 4 + 0]) | ((unsigned)bfbits(p[tt * 4 + 1]) << 16);
            pk[tt][1] = (unsigned)bfbits(p[tt * 4 + 2]) | ((unsigned)bfbits(p[tt * 4 + 3]) << 16);
        }
        const int srcA = ((g & 1) << 5) + c;
        const int srcB = srcA + 16;
#pragma unroll
        for (int kh = 0; kh < 2; ++kh) {
            const unsigned a0 = __shfl(pk[kh * 2][0], srcA), b0_ = __shfl(pk[kh * 2 + 1][0], srcA);
            const unsigned a1 = __shfl(pk[kh * 2][1], srcA), b1_ = __shfl(pk[kh * 2 + 1][1], srcA);
            const unsigned a2 = __shfl(pk[kh * 2][0], srcB), b2_ = __shfl(pk[kh * 2 + 1][0], srcB);
            const unsigned a3 = __shfl(pk[kh * 2][1], srcB), b3_ = __shfl(pk[kh * 2 + 1][1], srcB);
            union { bf8_t v; unsigned u[4]; } pf;
            const bool hi = (g & 2);
            pf.u[0] = hi ? b0_ : a0; pf.u[1] = hi ? b1_ : a1;
            pf.u[2] = hi ? b2_ : a2; pf.u[3] = hi ? b3_ : a3;
            const int kcol = (kh * 32 + 8 * g) ^ ((c & 7) << 3);
            const bf8_t vf0 = *(const bf8_t*)(Vt + c * 64 + kcol);
            const bf8_t vf1 = *(const bf8_t*)(Vt + (16 + c) * 64 + kcol);
            acc0 = MFMA16(vf0, pf.v, acc0);
            acc1 = MFMA16(vf1, pf.v, acc1);
        }
    }

    __syncthreads();
    const float invl = 1.f / l_run;
    float* O = smemf + wave * 528;
#pragma unroll
    for (int r = 0; r < 4; ++r) {
        O[c * 33 + 4 * g + r] = acc0[r] * invl;
        O[c * 33 + 16 + 4 * g + r] = acc1[r] * invl;
    }
    __syncthreads();
    {
        const int ql = lane >> 2, part = lane & 3;
        const int qg = q0 + ql;
        if (qg < NQ_) {
            union { bf8_t v; unsigned short u[8]; } pk;
#pragma unroll
            for (int u = 0; u < 8; ++u) pk.u[u] = bfbits(O[ql * 33 + part * 8 + u]);
            *(bf8_t*)(sa + ((long)qg * BS_ + b) * D_ + h * HD_ + part * 8) = pk.v;
        }
    }
}

// ---------------- msdeform: softmax + bilinear gather (8B/lane) ----------------
__global__ __launch_bounds__(256) void msdeform_kernel(
    const float* __restrict__ oa, const float* __restrict__ refp,
    const unsigned short* __restrict__ val, unsigned short* __restrict__ out)
{
    __shared__ float saw[128];
    __shared__ float redm[8], redi[8];
    __shared__ float swt[128][4];
    __shared__ int sidx[128][4];
    const int bq = blockIdx.x;
    const int b = bq / NQ_, q = bq % NQ_;
    const int t = threadIdx.x;
    if (t < 128) saw[t] = oa[(long)bq * 384 + 256 + t];
    __syncthreads();
    if (t < 8) {
        float mx = -1e30f;
        for (int i = 0; i < 16; ++i) mx = fmaxf(mx, saw[t * 16 + i]);
        float s = 0.f;
        for (int i = 0; i < 16; ++i) s += __expf(saw[t * 16 + i] - mx);
        redm[t] = mx; redi[t] = 1.f / s;
    }
    __syncthreads();
    if (t < 128) {
        const int h = t >> 4, lp = t & 15, l = lp >> 2, p = lp & 3;
        const float aw = __expf(saw[t] - redm[h]) * redi[h];
        const int Wi = (l == 0) ? 100 : (l == 1) ? 50 : (l == 2) ? 25 : 13;
        const int Hi = Wi;
        const int sl = (l == 0) ? 0 : (l == 1) ? 10000 : (l == 2) ? 12500 : 13125;
        const float offx = oa[(long)bq * 384 + h * 32 + l * 8 + p * 2 + 0];
        const float offy = oa[(long)bq * 384 + h * 32 + l * 8 + p * 2 + 1];
        const float refx = refp[(((long)q * BS_ + b) * 4 + l) * 2 + 0];
        const float refy = refp[(((long)q * BS_ + b) * 4 + l) * 2 + 1];
        const float fW = (float)Wi, fH = (float)Hi;
        const float x = (refx + offx / fW) * fW - 0.5f;
        const float y = (refy + offy / fH) * fH - 0.5f;
        const float x0f = floorf(x), y0f = floorf(y);
        const float fx = x - x0f, fy = y - y0f;
        const int ix = (int)x0f, iy = (int)y0f;
        const float wts[4] = {(1.f - fx) * (1.f - fy), fx * (1.f - fy),
                              (1.f - fx) * fy,          fx * fy};
        const int xs[4] = {ix, ix + 1, ix, ix + 1};
        const int ys[4] = {iy, iy, iy + 1, iy + 1};
#pragma unroll
        for (int tap = 0; tap < 4; ++tap) {
            const bool valid = (xs[tap] >= 0) & (xs[tap] < Wi) & (ys[tap] >= 0) & (ys[tap] < Hi);
            const int xc = min(max(xs[tap], 0), Wi - 1);
            const int yc = min(max(ys[tap], 0), Hi - 1);
            swt[t][tap] = valid ? aw * wts[tap] : 0.f;
            sidx[t][tap] = b * LMEM_ + sl + yc * Wi + xc;
        }
    }
    __syncthreads();
    const int h = t >> 5, r = t & 31, qd = r & 7, s = r >> 3;
    float a0 = 0.f, a1 = 0.f, a2 = 0.f, a3 = 0.f;
#pragma unroll
    for (int i = 0; i < 16; ++i) {
        const int j = h * 16 + i;
        const float wv = swt[j][s];
        const long base = (long)sidx[j][s] * D_ + h * HD_ + qd * 4;
        const uint2 raw = *(const uint2*)(val + base);
        a0 += wv * bf2f((unsigned short)(raw.x & 0xffff));
        a1 += wv * bf2f((unsigned short)(raw.x >> 16));
        a2 += wv * bf2f((unsigned short)(raw.y & 0xffff));
        a3 += wv * bf2f((unsigned short)(raw.y >> 16));
    }
    a0 += __shfl_xor(a0, 8); a0 += __shfl_xor(a0, 16);
    a1 += __shfl_xor(a1, 8); a1 += __shfl_xor(a1, 16);
    a2 += __shfl_xor(a2, 8); a2 += __shfl_xor(a2, 16);
    a3 += __shfl_xor(a3, 8); a3 += __shfl_xor(a3, 16);
    if (s == 0) {
        union { unsigned short u[4]; uint2 w; } pk;
        pk.u[0] = bfbits(a0); pk.u[1] = bfbits(a1); pk.u[2] = bfbits(a2); pk.u[3] = bfbits(a3);
        *(uint2*)(out + (long)bq * D_ + h * HD_ + qd * 4) = pk.w;
    }
}

// ---------------- LayerNorm: out = LN(inA[r] + inB[rb]); optional bf16 out ----
__global__ __launch_bounds__(256) void ln_kernel(
    const float* __restrict__ inA, const float* __restrict__ inB,
    const float* __restrict__ g, const float* __restrict__ be,
    float* __restrict__ out, const float* __restrict__ pos,
    unsigned short* __restrict__ bfOut, int swapB, int bfMode)
{
    const int r = blockIdx.x * 4 + (threadIdx.x >> 6);
    const int lane = threadIdx.x & 63;
    long rb = r;
    if (swapB) rb = (long)(r & 7) * NQ_ + (r >> 3);
    const float4 a4 = *(const float4*)(inA + (long)r * D_ + lane * 4);
    const float4 b4 = *(const float4*)(inB + rb * D_ + lane * 4);
    float x[4] = {a4.x + b4.x, a4.y + b4.y, a4.z + b4.z, a4.w + b4.w};
    float s = x[0] + x[1] + x[2] + x[3];
#pragma unroll
    for (int off = 32; off > 0; off >>= 1) s += __shfl_xor(s, off);
    const float mu = s * (1.f / D_);
    float v = 0.f;
#pragma unroll
    for (int cc = 0; cc < 4; ++cc) { const float dd = x[cc] - mu; v += dd * dd; }
#pragma unroll
    for (int off = 32; off > 0; off >>= 1) v += __shfl_xor(v, off);
    const float rs = rsqrtf(v * (1.f / D_) + 1e-5f);
    const float4 g4 = *(const float4*)(g + lane * 4);
    const float4 e4 = *(const float4*)(be + lane * 4);
    const float gg[4] = {g4.x, g4.y, g4.z, g4.w};
    const float ee[4] = {e4.x, e4.y, e4.z, e4.w};
    float y[4];
#pragma unroll
    for (int cc = 0; cc < 4; ++cc) y[cc] = (x[cc] - mu) * rs * gg[cc] + ee[cc];
    *(float4*)(out + (long)r * D_ + lane * 4) = make_float4(y[0], y[1], y[2], y[3]);
    if (bfMode) {
        float z[4] = {y[0], y[1], y[2], y[3]};
        long er = r;
        if (bfMode == 2) {
            const float4 p4 = *(const float4*)(pos + (long)r * D_ + lane * 4);
            z[0] += p4.x; z[1] += p4.y; z[2] += p4.z; z[3] += p4.w;
            er = (long)(r & 7) * NQ_ + (r >> 3);
        }
        union { unsigned short u[4]; uint2 w; } pk;
        pk.u[0] = bfbits(z[0]); pk.u[1] = bfbits(z[1]);
        pk.u[2] = bfbits(z[2]); pk.u[3] = bfbits(z[3]);
        *(uint2*)(bfOut + er * D_ + lane * 4) = pk.w;
    }
}

// ---------------------------------------------------------------------------
extern "C" void kernel_launch(void* const* d_in, const int* in_sizes, int n_in,
                              void* d_out, int out_size, void* d_ws, size_t ws_size,
                              hipStream_t stream) {
    const float* tgt   = (const float*)d_in[0];
    const float* pos   = (const float*)d_in[1];
    const float* refp  = (const float*)d_in[2];
    const float* mem   = (const float*)d_in[3];
    const float* ipw   = (const float*)d_in[6];
    const float* ipb   = (const float*)d_in[7];
    const float* opw   = (const float*)d_in[8];
    const float* opb   = (const float*)d_in[9];
    const float* sow   = (const float*)d_in[10];
    const float* sob   = (const float*)d_in[11];
    const float* aww   = (const float*)d_in[12];
    const float* awb   = (const float*)d_in[13];
    const float* vpw   = (const float*)d_in[14];
    const float* vpb   = (const float*)d_in[15];
    const float* outpw = (const float*)d_in[16];
    const float* outpb = (const float*)d_in[17];
    const float* l1w   = (const float*)d_in[18];
    const float* l1b   = (const float*)d_in[19];
    const float* l2w   = (const float*)d_in[20];
    const float* l2b   = (const float*)d_in[21];
    const float* n1g = (const float*)d_in[22]; const float* n1be = (const float*)d_in[23];
    const float* n2g = (const float*)d_in[24]; const float* n2be = (const float*)d_in[25];
    const float* n3g = (const float*)d_in[26]; const float* n3be = (const float*)d_in[27];

    // ---- workspace carve-up (no aliasing; ws is ~435MB) ----
    char* wsb = (char*)d_ws;
    auto alloc = [&](size_t bytes) { char* p = wsb; wsb += (bytes + 255) & ~(size_t)255; return p; };
    unsigned short* Wbf       = (unsigned short*)alloc(1015808 * 2);
    float*          biasAll   = (float*)alloc(896 * 4);
    unsigned short* QK_bf     = (unsigned short*)alloc(T * 4);    // 7200x512 bf16
    unsigned short* Vb_bf     = (unsigned short*)alloc(T * 2);
    unsigned short* sa_bf     = (unsigned short*)alloc(T * 2);
    float*          saproj    = (float*)alloc(T * 4);
    float*          t1        = (float*)alloc(T * 4);
    unsigned short* qplus2_bf = (unsigned short*)alloc(T * 2);
    float*          oa        = (float*)alloc((long)MTOK * 384 * 4);
    unsigned short* sampo_bf  = (unsigned short*)alloc(T * 2);
    float*          ca        = (float*)alloc(T * 4);
    float*          t2        = (float*)alloc(T * 4);
    unsigned short* t2_bf     = (unsigned short*)alloc(T * 2);
    unsigned short* ffnh_bf   = (unsigned short*)alloc((long)MTOK * DFF_ * 2);
    float*          ffno      = (float*)alloc(T * 4);
    unsigned short* val       = (unsigned short*)alloc((long)BS_ * LMEM_ * D_ * 2);
    // weight slices inside Wbf
    const unsigned short* wqk   = Wbf + 0;        // 512 x 256
    const unsigned short* wv    = Wbf + 131072;
    const unsigned short* wo    = Wbf + 196608;
    const unsigned short* wsoaw = Wbf + 262144;   // 384 x 256
    const unsigned short* wvp   = Wbf + 360448;
    const unsigned short* wop   = Wbf + 425984;
    const unsigned short* wl1   = Wbf + 491520;
    const unsigned short* wl2   = Wbf + 753664;
    const float* bias_qk = biasAll;
    const float* bias_oa = biasAll + 512;

    const dim3 blk(256);
    const dim3 g_m(57, 2);   // 7200 rows, 256 cols

    conv_weights<<<992, blk, 0, stream>>>(ipw, opw, sow, aww, vpw, outpw, l1w, l2w,
                                          ipb, sob, awb, Wbf, biasAll);
    // fused QK projection, A = tgt+pos (f32, fused add)
    gemm_f32a<true><<<dim3(57, 4), blk, 0, stream>>>(tgt, pos, wqk, bias_qk, QK_bf,
                                                     MTOK, QKS, D_, MTOK, 0, 1);
    // V projection, A = tgt
    gemm_f32a<true><<<g_m, blk, 0, stream>>>(tgt, nullptr, wv, ipb + 2 * D_, Vb_bf,
                                             MTOK, D_, D_, MTOK, 0, 1);
    // self-attention
    attn_mfma<<<dim3(64, 15), blk, 0, stream>>>(QK_bf, QK_bf + 256, Vb_bf, sa_bf);
    // out_proj
    gemm_mfma<false, false><<<g_m, blk, 0, stream>>>(sa_bf, wo, opb, saproj, MTOK, D_, D_);
    // t1 = LN2(tgt + saproj); qplus2_bf = bf16(t1 + pos) transposed (b,q)
    ln_kernel<<<1800, blk, 0, stream>>>(tgt, saproj, n2g, n2be, t1, pos, qplus2_bf, 0, 2);
    // value projection, A = memory rows (i,b) -> (b,i):  arow = i*8 + b
    gemm_f32a<true><<<dim3(831, 2), blk, 0, stream>>>(mem, nullptr, wvp, vpb, val,
                                                      BS_ * LMEM_, D_, D_, LMEM_, 1, BS_);
    // fused samp_off + attn_w (N=384, f32 out)
    gemm_mfma<false, false><<<dim3(57, 3), blk, 0, stream>>>(qplus2_bf, wsoaw, bias_oa, oa, MTOK, 384, D_);
    // deformable sampling
    msdeform_kernel<<<7200, blk, 0, stream>>>(oa, refp, val, sampo_bf);
    // output projection
    gemm_mfma<false, false><<<g_m, blk, 0, stream>>>(sampo_bf, wop, outpb, ca, MTOK, D_, D_);
    // t2 = LN1(t1 + ca^T) + bf16 copy
    ln_kernel<<<1800, blk, 0, stream>>>(t1, ca, n1g, n1be, t2, nullptr, t2_bf, 1, 1);
    // FFN
    gemm_mfma<true, true><<<dim3(57, 8), blk, 0, stream>>>(t2_bf, wl1, l1b, ffnh_bf, MTOK, DFF_, D_);
    gemm_mfma<false, false><<<g_m, blk, 0, stream>>>(ffnh_bf, wl2, l2b, ffno, MTOK, D_, DFF_);
    // out = LN3(t2 + ffn)
    ln_kernel<<<1800, blk, 0, stream>>>(t2, ffno, n3g, n3be, (float*)d_out, nullptr, nullptr, 0, 0);
}